// Round 3
// baseline (3490.526 us; speedup 1.0000x reference)
//
#include <hip/hip_runtime.h>

// STGAT fully-fused: one block per 64-ped graph, all state LDS/register-resident.
// Round 3: launch_bounds(512,1) — round 2's (512,4) was interpreted as 4 blocks/CU
// -> VGPR capped at 64 -> decoder acc[36] spilled to scratch (1.9 GB/dispatch HBM
// traffic). Cap >=256 removes all spills. Decoder trimmed to 2 barriers/step
// (redundant cross-wave reduce keeps px in registers).

#define OBS 8
#define FUT 12
#define NPED 64
#define HT_ 32
#define HG_ 32
#define NZ_ 8
#define HP_ 72
#define NGR 1024
#define NTOT (NGR * NPED)

__device__ __forceinline__ float sigf(float x) { return 1.0f / (1.0f + __expf(-x)); }
__device__ __forceinline__ float tanh_(float x) {
    float e = __expf(2.0f * x);
    return 1.0f - 2.0f / (e + 1.0f);
}
__device__ __forceinline__ float leaky(float x) { return (x > 0.0f) ? x : 0.2f * x; }

__global__ __launch_bounds__(512, 1)
void stgat_fused(const float* __restrict__ obs,       // (8,N,3)
                 const float* __restrict__ zin,       // (G,8)
                 const float* __restrict__ traj_h0,   // (N,32)
                 const float* __restrict__ traj_c0,
                 const float* __restrict__ graph_h0,
                 const float* __restrict__ graph_c0,
                 const float* __restrict__ w_ih_t,    // (128,3)
                 const float* __restrict__ w_hh_t,    // (128,32)
                 const float* __restrict__ b_ih_t,
                 const float* __restrict__ b_hh_t,
                 const float* __restrict__ g1w,       // (4,32,16)
                 const float* __restrict__ g1as,      // (4,16)
                 const float* __restrict__ g1ad,
                 const float* __restrict__ g1b,       // (16)
                 const float* __restrict__ g2w,       // (64,32)
                 const float* __restrict__ g2as,      // (32)
                 const float* __restrict__ g2ad,
                 const float* __restrict__ g2b,       // (32)
                 const float* __restrict__ w_ih_g,    // (128,32)
                 const float* __restrict__ w_hh_g,    // (128,32)
                 const float* __restrict__ b_ih_g,
                 const float* __restrict__ b_hh_g,
                 const float* __restrict__ w_ih_p,    // (288,2)
                 const float* __restrict__ w_hh_p,    // (288,72)
                 const float* __restrict__ b_ih_p,
                 const float* __restrict__ b_hh_p,
                 const float* __restrict__ w_out,     // (2,72)
                 const float* __restrict__ b_out,     // (2)
                 float* __restrict__ out)             // (12,N,2)
{
    const int g    = blockIdx.x;
    const int lane = threadIdx.x & 63;
    const int wv   = __builtin_amdgcn_readfirstlane((int)(threadIdx.x >> 6));
    const int n    = g * NPED + lane;

    __shared__ float s_th[HT_ * 64];      // 8 KB
    __shared__ float s_gh[HG_ * 64];      // 8 KB
    __shared__ float s_scr[14976];        // ~58.5 KB, phase-overlaid

    // ---- encoder overlay ----
    float* hp1 = s_scr;            // [64][64]
    float* x2  = s_scr + 4096;     // [64][64]
    float* xn  = s_scr + 8192;     // [32][64]
    float* hp2 = s_scr + 10240;    // [32][64]
    float* gin = s_scr + 12288;    // [32][64]
    float* s1  = s_scr + 14336;    // [4][64]
    float* d1  = s_scr + 14592;    // [4][64]
    float* s2  = s_scr + 14848;    // [64]
    float* d2  = s_scr + 14912;    // [64]
    // ---- decoder overlay ----
    float* hA   = s_scr;           // [72][64]
    float* hB   = s_scr + 4608;    // [72][64]
    float* red0 = s_scr + 10240;   // [8][64]
    float* red1 = s_scr + 10752;   // [8][64]

    float cT[4], cG[4];
    #pragma unroll
    for (int r = 0; r < 4; ++r) {
        int j = wv * 4 + r;
        s_th[j * 64 + lane] = traj_h0[n * HT_ + j];
        s_gh[j * 64 + lane] = graph_h0[n * HG_ + j];
        cT[r] = traj_c0[n * HT_ + j];
        cG[r] = graph_c0[n * HG_ + j];
    }
    __syncthreads();

    for (int t = 0; t < OBS; ++t) {
        // ===== traj LSTM: wave wv computes i/f/g/o gates for j = wv*4+r ====
        float nh[4];
        {
            const float x0 = obs[(t * NTOT + n) * 3 + 0];
            const float x1 = obs[(t * NTOT + n) * 3 + 1];
            const float xv = obs[(t * NTOT + n) * 3 + 2];
            float acc[16];
            #pragma unroll
            for (int ty = 0; ty < 4; ++ty)
                #pragma unroll
                for (int r = 0; r < 4; ++r) {
                    int gate = ty * 32 + wv * 4 + r;
                    acc[ty * 4 + r] = b_ih_t[gate] + b_hh_t[gate]
                                    + w_ih_t[gate * 3 + 0] * x0
                                    + w_ih_t[gate * 3 + 1] * x1
                                    + w_ih_t[gate * 3 + 2] * xv;
                }
            for (int k8 = 0; k8 < 4; ++k8) {
                float hk[8];
                #pragma unroll
                for (int i = 0; i < 8; ++i) hk[i] = s_th[(k8 * 8 + i) * 64 + lane];
                #pragma unroll
                for (int ty = 0; ty < 4; ++ty)
                    #pragma unroll
                    for (int r = 0; r < 4; ++r)
                        #pragma unroll
                        for (int i = 0; i < 8; ++i)
                            acc[ty * 4 + r] += w_hh_t[(ty * 32 + wv * 4 + r) * HT_ + k8 * 8 + i] * hk[i];
            }
            #pragma unroll
            for (int r = 0; r < 4; ++r) {
                float c = sigf(acc[4 + r]) * cT[r] + sigf(acc[r]) * tanh_(acc[8 + r]);
                cT[r] = c;
                nh[r] = sigf(acc[12 + r]) * tanh_(c);
            }
        }
        __syncthreads();                       // all reads of old s_th done
        // write h + fused inorm (value is in-register; norm = 64-lane shuffle)
        #pragma unroll
        for (int r = 0; r < 4; ++r) {
            int f = wv * 4 + r;
            s_th[f * 64 + lane] = nh[r];
            float v = nh[r];
            float sm = v, sq = v * v;
            #pragma unroll
            for (int m = 1; m < 64; m <<= 1) { sm += __shfl_xor(sm, m); sq += __shfl_xor(sq, m); }
            float mean = sm * (1.0f / 64.0f);
            float var  = sq * (1.0f / 64.0f) - mean * mean;
            xn[f * 64 + lane] = (v - mean) * rsqrtf(var + 1e-5f);
        }
        __syncthreads();
        // ===== GAT1 projection: wave (h_, o0) -> hp1 rows h_*16+o0..+8 =====
        {
            const int h_ = wv >> 1;
            const int o0 = (wv & 1) * 8;
            float acc[8];
            #pragma unroll
            for (int q = 0; q < 8; ++q) acc[q] = 0.0f;
            for (int k8 = 0; k8 < 4; ++k8) {
                float xk[8];
                #pragma unroll
                for (int i = 0; i < 8; ++i) xk[i] = xn[(k8 * 8 + i) * 64 + lane];
                #pragma unroll
                for (int i = 0; i < 8; ++i)
                    #pragma unroll
                    for (int q = 0; q < 8; ++q)
                        acc[q] += g1w[h_ * 512 + (k8 * 8 + i) * 16 + o0 + q] * xk[i];
            }
            #pragma unroll
            for (int q = 0; q < 8; ++q) hp1[(h_ * 16 + o0 + q) * 64 + lane] = acc[q];
        }
        __syncthreads();
        // ===== s1, d1 =====
        {
            const int h_ = wv & 3;
            const float* av = (wv < 4) ? g1as : g1ad;
            float acc = 0.0f;
            #pragma unroll
            for (int o = 0; o < 16; ++o) acc += hp1[(h_ * 16 + o) * 64 + lane] * av[h_ * 16 + o];
            float* dst = (wv < 4) ? s1 : d1;
            dst[h_ * 64 + lane] = acc;
        }
        __syncthreads();
        // ===== attn1: two-pass softmax-apply + elu + fused inorm -> x2 =====
        {
            const int h_ = wv >> 1;
            const int o0 = (wv & 1) * 8;
            const float sv = s1[h_ * 64 + lane];
            float mx = -1e30f;
            #pragma unroll
            for (int m4 = 0; m4 < 16; ++m4) {
                float4 dv = *reinterpret_cast<const float4*>(&d1[h_ * 64 + m4 * 4]);
                mx = fmaxf(mx, leaky(sv + dv.x));
                mx = fmaxf(mx, leaky(sv + dv.y));
                mx = fmaxf(mx, leaky(sv + dv.z));
                mx = fmaxf(mx, leaky(sv + dv.w));
            }
            float sum = 0.0f;
            float acc[8];
            #pragma unroll
            for (int q = 0; q < 8; ++q) acc[q] = 0.0f;
            #pragma unroll
            for (int m4 = 0; m4 < 16; ++m4) {
                float4 dv = *reinterpret_cast<const float4*>(&d1[h_ * 64 + m4 * 4]);
                float e0 = __expf(leaky(sv + dv.x) - mx);
                float e1 = __expf(leaky(sv + dv.y) - mx);
                float e2 = __expf(leaky(sv + dv.z) - mx);
                float e3 = __expf(leaky(sv + dv.w) - mx);
                sum += e0 + e1 + e2 + e3;
                #pragma unroll
                for (int q = 0; q < 8; ++q) {
                    float4 hv = *reinterpret_cast<const float4*>(&hp1[(h_ * 16 + o0 + q) * 64 + m4 * 4]);
                    acc[q] += e0 * hv.x + e1 * hv.y + e2 * hv.z + e3 * hv.w;
                }
            }
            float rs = 1.0f / sum;
            #pragma unroll
            for (int q = 0; q < 8; ++q) {
                float v = acc[q] * rs + g1b[o0 + q];
                v = (v > 0.0f) ? v : (__expf(v) - 1.0f);          // elu
                float sm = v, sq = v * v;                          // fused inorm
                #pragma unroll
                for (int m = 1; m < 64; m <<= 1) { sm += __shfl_xor(sm, m); sq += __shfl_xor(sq, m); }
                float mean = sm * (1.0f / 64.0f);
                float var  = sq * (1.0f / 64.0f) - mean * mean;
                x2[(h_ * 16 + o0 + q) * 64 + lane] = (v - mean) * rsqrtf(var + 1e-5f);
            }
        }
        __syncthreads();
        // ===== GAT2 projection: wave wv -> hp2 rows wv*4..+4 =====
        {
            float acc[4];
            #pragma unroll
            for (int q = 0; q < 4; ++q) acc[q] = 0.0f;
            for (int k8 = 0; k8 < 8; ++k8) {
                float xk[8];
                #pragma unroll
                for (int i = 0; i < 8; ++i) xk[i] = x2[(k8 * 8 + i) * 64 + lane];
                #pragma unroll
                for (int i = 0; i < 8; ++i)
                    #pragma unroll
                    for (int q = 0; q < 4; ++q)
                        acc[q] += g2w[(k8 * 8 + i) * 32 + wv * 4 + q] * xk[i];
            }
            #pragma unroll
            for (int q = 0; q < 4; ++q) hp2[(wv * 4 + q) * 64 + lane] = acc[q];
        }
        __syncthreads();
        // ===== s2, d2 =====
        if (wv == 0) {
            float acc = 0.0f;
            #pragma unroll
            for (int o = 0; o < 32; ++o) acc += hp2[o * 64 + lane] * g2as[o];
            s2[lane] = acc;
        } else if (wv == 1) {
            float acc = 0.0f;
            #pragma unroll
            for (int o = 0; o < 32; ++o) acc += hp2[o * 64 + lane] * g2ad[o];
            d2[lane] = acc;
        }
        __syncthreads();
        // ===== attn2: two-pass, wave wv -> gin rows wv*4..+4 =====
        {
            const float sv = s2[lane];
            float mx = -1e30f;
            #pragma unroll
            for (int m4 = 0; m4 < 16; ++m4) {
                float4 dv = *reinterpret_cast<const float4*>(&d2[m4 * 4]);
                mx = fmaxf(mx, leaky(sv + dv.x));
                mx = fmaxf(mx, leaky(sv + dv.y));
                mx = fmaxf(mx, leaky(sv + dv.z));
                mx = fmaxf(mx, leaky(sv + dv.w));
            }
            float sum = 0.0f;
            float acc[4];
            #pragma unroll
            for (int q = 0; q < 4; ++q) acc[q] = 0.0f;
            #pragma unroll
            for (int m4 = 0; m4 < 16; ++m4) {
                float4 dv = *reinterpret_cast<const float4*>(&d2[m4 * 4]);
                float e0 = __expf(leaky(sv + dv.x) - mx);
                float e1 = __expf(leaky(sv + dv.y) - mx);
                float e2 = __expf(leaky(sv + dv.z) - mx);
                float e3 = __expf(leaky(sv + dv.w) - mx);
                sum += e0 + e1 + e2 + e3;
                #pragma unroll
                for (int q = 0; q < 4; ++q) {
                    float4 hv = *reinterpret_cast<const float4*>(&hp2[(wv * 4 + q) * 64 + m4 * 4]);
                    acc[q] += e0 * hv.x + e1 * hv.y + e2 * hv.z + e3 * hv.w;
                }
            }
            float rs = 1.0f / sum;
            #pragma unroll
            for (int q = 0; q < 4; ++q)
                gin[(wv * 4 + q) * 64 + lane] = acc[q] * rs + g2b[wv * 4 + q];
        }
        __syncthreads();
        // ===== graph LSTM: gates in regs =====
        float ng[4];
        {
            float acc[16];
            #pragma unroll
            for (int ty = 0; ty < 4; ++ty)
                #pragma unroll
                for (int r = 0; r < 4; ++r) {
                    int gate = ty * 32 + wv * 4 + r;
                    acc[ty * 4 + r] = b_ih_g[gate] + b_hh_g[gate];
                }
            for (int k8 = 0; k8 < 4; ++k8) {
                float xk[8], hk[8];
                #pragma unroll
                for (int i = 0; i < 8; ++i) {
                    xk[i] = gin[(k8 * 8 + i) * 64 + lane];
                    hk[i] = s_gh[(k8 * 8 + i) * 64 + lane];
                }
                #pragma unroll
                for (int ty = 0; ty < 4; ++ty)
                    #pragma unroll
                    for (int r = 0; r < 4; ++r)
                        #pragma unroll
                        for (int i = 0; i < 8; ++i)
                            acc[ty * 4 + r] += w_ih_g[(ty * 32 + wv * 4 + r) * 32 + k8 * 8 + i] * xk[i]
                                             + w_hh_g[(ty * 32 + wv * 4 + r) * 32 + k8 * 8 + i] * hk[i];
            }
            #pragma unroll
            for (int r = 0; r < 4; ++r) {
                float c = sigf(acc[4 + r]) * cG[r] + sigf(acc[r]) * tanh_(acc[8 + r]);
                cG[r] = c;
                ng[r] = sigf(acc[12 + r]) * tanh_(c);
            }
        }
        __syncthreads();                       // all reads of old s_gh done
        #pragma unroll
        for (int r = 0; r < 4; ++r) s_gh[(wv * 4 + r) * 64 + lane] = ng[r];
        // next read of s_gh is behind >=1 barrier in the next t-iteration
    } // t loop

    __syncthreads();                           // fence final s_gh writes

    // ======================= decoder (12 steps) ============================
    float cA[9], cB[9];
    #pragma unroll
    for (int r = 0; r < 9; ++r) { cA[r] = 0.0f; cB[r] = 0.0f; }
    #pragma unroll
    for (int r = 0; r < 9; ++r) {
        int j = wv * 9 + r;
        float va, vb;
        if (j < 32)      { va = s_th[j * 64 + lane];              vb = 0.0f; }
        else if (j < 64) { float gv = s_gh[(j - 32) * 64 + lane]; va = gv; vb = gv; }
        else             { float zv = zin[g * NZ_ + (j - 64)];    va = zv; vb = zv; }
        hA[j * 64 + lane] = va;
        hB[j * 64 + lane] = vb;
    }
    float px0 = obs[(7 * NTOT + n) * 3 + 0];
    float px1 = obs[(7 * NTOT + n) * 3 + 1];
    __syncthreads();

    for (int st = 0; st < FUT; ++st) {
        float nhA[9], nhB[9];
        // ---- gates+update A (registers only; reads hA) ----
        {
            float acc[36];
            #pragma unroll
            for (int ty = 0; ty < 4; ++ty)
                #pragma unroll
                for (int r = 0; r < 9; ++r) {
                    int gate = ty * 72 + wv * 9 + r;
                    acc[ty * 9 + r] = b_ih_p[gate] + b_hh_p[gate]
                                    + w_ih_p[gate * 2 + 0] * px0
                                    + w_ih_p[gate * 2 + 1] * px1;
                }
            for (int k8 = 0; k8 < 9; ++k8) {
                float hk[8];
                #pragma unroll
                for (int i = 0; i < 8; ++i) hk[i] = hA[(k8 * 8 + i) * 64 + lane];
                #pragma unroll
                for (int ty = 0; ty < 4; ++ty)
                    #pragma unroll
                    for (int r = 0; r < 9; ++r)
                        #pragma unroll
                        for (int i = 0; i < 8; ++i)
                            acc[ty * 9 + r] += w_hh_p[(ty * 72 + wv * 9 + r) * HP_ + k8 * 8 + i] * hk[i];
            }
            #pragma unroll
            for (int r = 0; r < 9; ++r) {
                float c = sigf(acc[9 + r]) * cA[r] + sigf(acc[r]) * tanh_(acc[18 + r]);
                cA[r] = c;
                nhA[r] = sigf(acc[27 + r]) * tanh_(c);
            }
        }
        // ---- gates+update B (reads hB) ----
        {
            float acc[36];
            #pragma unroll
            for (int ty = 0; ty < 4; ++ty)
                #pragma unroll
                for (int r = 0; r < 9; ++r) {
                    int gate = ty * 72 + wv * 9 + r;
                    acc[ty * 9 + r] = b_ih_p[gate] + b_hh_p[gate]
                                    + w_ih_p[gate * 2 + 0] * px0
                                    + w_ih_p[gate * 2 + 1] * px1;
                }
            for (int k8 = 0; k8 < 9; ++k8) {
                float hk[8];
                #pragma unroll
                for (int i = 0; i < 8; ++i) hk[i] = hB[(k8 * 8 + i) * 64 + lane];
                #pragma unroll
                for (int ty = 0; ty < 4; ++ty)
                    #pragma unroll
                    for (int r = 0; r < 9; ++r)
                        #pragma unroll
                        for (int i = 0; i < 8; ++i)
                            acc[ty * 9 + r] += w_hh_p[(ty * 72 + wv * 9 + r) * HP_ + k8 * 8 + i] * hk[i];
            }
            #pragma unroll
            for (int r = 0; r < 9; ++r) {
                float c = sigf(acc[9 + r]) * cB[r] + sigf(acc[r]) * tanh_(acc[18 + r]);
                cB[r] = c;
                nhB[r] = sigf(acc[27 + r]) * tanh_(c);
            }
        }
        // ---- local partial of output dot ----
        float po0 = 0.0f, po1 = 0.0f;
        #pragma unroll
        for (int r = 0; r < 9; ++r) {
            float dh = nhA[r] - nhB[r];
            po0 += w_out[wv * 9 + r] * dh;
            po1 += w_out[HP_ + wv * 9 + r] * dh;
        }
        __syncthreads();                       // B1: all k-loop reads of hA/hB done
        #pragma unroll
        for (int r = 0; r < 9; ++r) {
            hA[(wv * 9 + r) * 64 + lane] = nhA[r];
            hB[(wv * 9 + r) * 64 + lane] = nhB[r];
        }
        red0[wv * 64 + lane] = po0;
        red1[wv * 64 + lane] = po1;
        __syncthreads();                       // B2: h + partials visible
        // all waves reduce redundantly -> px stays in registers, no 3rd barrier
        float o0 = b_out[0], o1 = b_out[1];
        #pragma unroll
        for (int w = 0; w < 8; ++w) { o0 += red0[w * 64 + lane]; o1 += red1[w * 64 + lane]; }
        if (wv == 0) {
            out[(st * NTOT + n) * 2 + 0] = o0;
            out[(st * NTOT + n) * 2 + 1] = o1;
        }
        px0 = o0; px1 = o1;
    }
}

extern "C" void kernel_launch(void* const* d_in, const int* in_sizes, int n_in,
                              void* d_out, int out_size, void* d_ws, size_t ws_size,
                              hipStream_t stream) {
    (void)in_sizes; (void)n_in; (void)out_size; (void)d_ws; (void)ws_size;
    stgat_fused<<<dim3(NGR), dim3(512), 0, stream>>>(
        (const float*)d_in[0],  (const float*)d_in[1],  (const float*)d_in[2],
        (const float*)d_in[3],  (const float*)d_in[4],  (const float*)d_in[5],
        (const float*)d_in[6],  (const float*)d_in[7],  (const float*)d_in[8],
        (const float*)d_in[9],  (const float*)d_in[10], (const float*)d_in[11],
        (const float*)d_in[12], (const float*)d_in[13], (const float*)d_in[14],
        (const float*)d_in[15], (const float*)d_in[16], (const float*)d_in[17],
        (const float*)d_in[18], (const float*)d_in[19], (const float*)d_in[20],
        (const float*)d_in[21], (const float*)d_in[22], (const float*)d_in[23],
        (const float*)d_in[24], (const float*)d_in[25], (const float*)d_in[26],
        (const float*)d_in[27],
        (float*)d_out);
}

// Round 4
// 1838.937 us; speedup vs baseline: 1.8981x; 1.8981x over previous
//
#include <hip/hip_runtime.h>

// STGAT fully-fused: one block per 64-ped graph.
// Round 4: decoder rewritten on MFMA (bf16 hi/lo split, 3 products).
//   gates[64x288] = A[64x96] . W[96x288], gate' = 4j+ty permutation,
//   W fragments VGPR-persistent (no s_load stream), h in LDS as bf16 hi/lo.
// Encoder unchanged from round 3.

#define OBS 8
#define FUT 12
#define NPED 64
#define HT_ 32
#define HG_ 32
#define NZ_ 8
#define HP_ 72
#define NGR 1024
#define NTOT (NGR * NPED)
#define AP 104   // Apack row stride in ushorts (208B: 16B-aligned, conflict-light)

typedef __attribute__((ext_vector_type(8))) short short8_t;
typedef __attribute__((ext_vector_type(4))) float f32x4;
typedef unsigned short u16;

__device__ __forceinline__ float sigf(float x) { return 1.0f / (1.0f + __expf(-x)); }
__device__ __forceinline__ float tanh_(float x) {
    float e = __expf(2.0f * x);
    return 1.0f - 2.0f / (e + 1.0f);
}
__device__ __forceinline__ float leaky(float x) { return (x > 0.0f) ? x : 0.2f * x; }
__device__ __forceinline__ u16 bhi(float v) {              // round-to-nearest-even bf16
    unsigned u = __float_as_uint(v);
    return (u16)((u + 0x7FFFu + ((u >> 16) & 1u)) >> 16);
}
__device__ __forceinline__ float bf2f(u16 h) { return __uint_as_float(((unsigned)h) << 16); }

// 4x4 transpose across 4-lane group x 4 regs, then LSTM pointwise update.
__device__ __forceinline__ void xpose_update(f32x4 acc, int lane, float& cstate, float& h2out) {
    float v0 = acc[0], v1 = acc[1], v2 = acc[2], v3 = acc[3];
    float s0 = __shfl_xor(v0, 1), s1 = __shfl_xor(v1, 1);
    float s2 = __shfl_xor(v2, 1), s3 = __shfl_xor(v3, 1);
    bool b0 = (lane & 1);
    float u0 = b0 ? s1 : v0;
    float u1 = b0 ? v1 : s0;
    float u2 = b0 ? s3 : v2;
    float u3 = b0 ? v3 : s2;
    float t0 = __shfl_xor(u0, 2), t1 = __shfl_xor(u1, 2);
    float t2 = __shfl_xor(u2, 2), t3 = __shfl_xor(u3, 2);
    bool b1 = (lane & 2);
    float w0 = b1 ? t2 : u0;   // i
    float w1 = b1 ? t3 : u1;   // f
    float w2 = b1 ? u2 : t0;   // g
    float w3 = b1 ? u3 : t1;   // o
    float c2 = sigf(w1) * cstate + sigf(w0) * tanh_(w2);
    cstate = c2;
    h2out = sigf(w3) * tanh_(c2);
}

__global__ __launch_bounds__(512, 1)
void stgat_fused(const float* __restrict__ obs,       // (8,N,3)
                 const float* __restrict__ zin,       // (G,8)
                 const float* __restrict__ traj_h0,   // (N,32)
                 const float* __restrict__ traj_c0,
                 const float* __restrict__ graph_h0,
                 const float* __restrict__ graph_c0,
                 const float* __restrict__ w_ih_t,    // (128,3)
                 const float* __restrict__ w_hh_t,    // (128,32)
                 const float* __restrict__ b_ih_t,
                 const float* __restrict__ b_hh_t,
                 const float* __restrict__ g1w,       // (4,32,16)
                 const float* __restrict__ g1as,      // (4,16)
                 const float* __restrict__ g1ad,
                 const float* __restrict__ g1b,       // (16)
                 const float* __restrict__ g2w,       // (64,32)
                 const float* __restrict__ g2as,      // (32)
                 const float* __restrict__ g2ad,
                 const float* __restrict__ g2b,       // (32)
                 const float* __restrict__ w_ih_g,    // (128,32)
                 const float* __restrict__ w_hh_g,    // (128,32)
                 const float* __restrict__ b_ih_g,
                 const float* __restrict__ b_hh_g,
                 const float* __restrict__ w_ih_p,    // (288,2)
                 const float* __restrict__ w_hh_p,    // (288,72)
                 const float* __restrict__ b_ih_p,
                 const float* __restrict__ b_hh_p,
                 const float* __restrict__ w_out,     // (2,72)
                 const float* __restrict__ b_out,     // (2)
                 float* __restrict__ out)             // (12,N,2)
{
    const int g    = blockIdx.x;
    const int lane = threadIdx.x & 63;
    const int wv   = __builtin_amdgcn_readfirstlane((int)(threadIdx.x >> 6));
    const int n    = g * NPED + lane;

    __shared__ float s_th[HT_ * 64];      // 8 KB
    __shared__ float s_gh[HG_ * 64];      // 8 KB
    __shared__ float s_scr[14976];        // ~58.5 KB, phase-overlaid

    // ---- encoder overlay ----
    float* hp1 = s_scr;            // [64][64]
    float* x2  = s_scr + 4096;     // [64][64]
    float* xn  = s_scr + 8192;     // [32][64]
    float* hp2 = s_scr + 10240;    // [32][64]
    float* gin = s_scr + 12288;    // [32][64]
    float* s1  = s_scr + 14336;    // [4][64]
    float* d1  = s_scr + 14592;    // [4][64]
    float* s2  = s_scr + 14848;    // [64]
    float* d2  = s_scr + 14912;    // [64]

    float cT[4], cG[4];
    #pragma unroll
    for (int r = 0; r < 4; ++r) {
        int j = wv * 4 + r;
        s_th[j * 64 + lane] = traj_h0[n * HT_ + j];
        s_gh[j * 64 + lane] = graph_h0[n * HG_ + j];
        cT[r] = traj_c0[n * HT_ + j];
        cG[r] = graph_c0[n * HG_ + j];
    }
    __syncthreads();

    for (int t = 0; t < OBS; ++t) {
        // ===== traj LSTM: wave wv computes i/f/g/o gates for j = wv*4+r ====
        float nh[4];
        {
            const float x0 = obs[(t * NTOT + n) * 3 + 0];
            const float x1 = obs[(t * NTOT + n) * 3 + 1];
            const float xv = obs[(t * NTOT + n) * 3 + 2];
            float acc[16];
            #pragma unroll
            for (int ty = 0; ty < 4; ++ty)
                #pragma unroll
                for (int r = 0; r < 4; ++r) {
                    int gate = ty * 32 + wv * 4 + r;
                    acc[ty * 4 + r] = b_ih_t[gate] + b_hh_t[gate]
                                    + w_ih_t[gate * 3 + 0] * x0
                                    + w_ih_t[gate * 3 + 1] * x1
                                    + w_ih_t[gate * 3 + 2] * xv;
                }
            for (int k8 = 0; k8 < 4; ++k8) {
                float hk[8];
                #pragma unroll
                for (int i = 0; i < 8; ++i) hk[i] = s_th[(k8 * 8 + i) * 64 + lane];
                #pragma unroll
                for (int ty = 0; ty < 4; ++ty)
                    #pragma unroll
                    for (int r = 0; r < 4; ++r)
                        #pragma unroll
                        for (int i = 0; i < 8; ++i)
                            acc[ty * 4 + r] += w_hh_t[(ty * 32 + wv * 4 + r) * HT_ + k8 * 8 + i] * hk[i];
            }
            #pragma unroll
            for (int r = 0; r < 4; ++r) {
                float c = sigf(acc[4 + r]) * cT[r] + sigf(acc[r]) * tanh_(acc[8 + r]);
                cT[r] = c;
                nh[r] = sigf(acc[12 + r]) * tanh_(c);
            }
        }
        __syncthreads();
        #pragma unroll
        for (int r = 0; r < 4; ++r) {
            int f = wv * 4 + r;
            s_th[f * 64 + lane] = nh[r];
            float v = nh[r];
            float sm = v, sq = v * v;
            #pragma unroll
            for (int m = 1; m < 64; m <<= 1) { sm += __shfl_xor(sm, m); sq += __shfl_xor(sq, m); }
            float mean = sm * (1.0f / 64.0f);
            float var  = sq * (1.0f / 64.0f) - mean * mean;
            xn[f * 64 + lane] = (v - mean) * rsqrtf(var + 1e-5f);
        }
        __syncthreads();
        // ===== GAT1 projection =====
        {
            const int h_ = wv >> 1;
            const int o0 = (wv & 1) * 8;
            float acc[8];
            #pragma unroll
            for (int q = 0; q < 8; ++q) acc[q] = 0.0f;
            for (int k8 = 0; k8 < 4; ++k8) {
                float xk[8];
                #pragma unroll
                for (int i = 0; i < 8; ++i) xk[i] = xn[(k8 * 8 + i) * 64 + lane];
                #pragma unroll
                for (int i = 0; i < 8; ++i)
                    #pragma unroll
                    for (int q = 0; q < 8; ++q)
                        acc[q] += g1w[h_ * 512 + (k8 * 8 + i) * 16 + o0 + q] * xk[i];
            }
            #pragma unroll
            for (int q = 0; q < 8; ++q) hp1[(h_ * 16 + o0 + q) * 64 + lane] = acc[q];
        }
        __syncthreads();
        // ===== s1, d1 =====
        {
            const int h_ = wv & 3;
            const float* av = (wv < 4) ? g1as : g1ad;
            float acc = 0.0f;
            #pragma unroll
            for (int o = 0; o < 16; ++o) acc += hp1[(h_ * 16 + o) * 64 + lane] * av[h_ * 16 + o];
            float* dst = (wv < 4) ? s1 : d1;
            dst[h_ * 64 + lane] = acc;
        }
        __syncthreads();
        // ===== attn1: two-pass softmax + elu + fused inorm -> x2 =====
        {
            const int h_ = wv >> 1;
            const int o0 = (wv & 1) * 8;
            const float sv = s1[h_ * 64 + lane];
            float mx = -1e30f;
            #pragma unroll
            for (int m4 = 0; m4 < 16; ++m4) {
                float4 dv = *reinterpret_cast<const float4*>(&d1[h_ * 64 + m4 * 4]);
                mx = fmaxf(mx, leaky(sv + dv.x));
                mx = fmaxf(mx, leaky(sv + dv.y));
                mx = fmaxf(mx, leaky(sv + dv.z));
                mx = fmaxf(mx, leaky(sv + dv.w));
            }
            float sum = 0.0f;
            float acc[8];
            #pragma unroll
            for (int q = 0; q < 8; ++q) acc[q] = 0.0f;
            #pragma unroll
            for (int m4 = 0; m4 < 16; ++m4) {
                float4 dv = *reinterpret_cast<const float4*>(&d1[h_ * 64 + m4 * 4]);
                float e0 = __expf(leaky(sv + dv.x) - mx);
                float e1 = __expf(leaky(sv + dv.y) - mx);
                float e2 = __expf(leaky(sv + dv.z) - mx);
                float e3 = __expf(leaky(sv + dv.w) - mx);
                sum += e0 + e1 + e2 + e3;
                #pragma unroll
                for (int q = 0; q < 8; ++q) {
                    float4 hv = *reinterpret_cast<const float4*>(&hp1[(h_ * 16 + o0 + q) * 64 + m4 * 4]);
                    acc[q] += e0 * hv.x + e1 * hv.y + e2 * hv.z + e3 * hv.w;
                }
            }
            float rs = 1.0f / sum;
            #pragma unroll
            for (int q = 0; q < 8; ++q) {
                float v = acc[q] * rs + g1b[o0 + q];
                v = (v > 0.0f) ? v : (__expf(v) - 1.0f);
                float sm = v, sq = v * v;
                #pragma unroll
                for (int m = 1; m < 64; m <<= 1) { sm += __shfl_xor(sm, m); sq += __shfl_xor(sq, m); }
                float mean = sm * (1.0f / 64.0f);
                float var  = sq * (1.0f / 64.0f) - mean * mean;
                x2[(h_ * 16 + o0 + q) * 64 + lane] = (v - mean) * rsqrtf(var + 1e-5f);
            }
        }
        __syncthreads();
        // ===== GAT2 projection =====
        {
            float acc[4];
            #pragma unroll
            for (int q = 0; q < 4; ++q) acc[q] = 0.0f;
            for (int k8 = 0; k8 < 8; ++k8) {
                float xk[8];
                #pragma unroll
                for (int i = 0; i < 8; ++i) xk[i] = x2[(k8 * 8 + i) * 64 + lane];
                #pragma unroll
                for (int i = 0; i < 8; ++i)
                    #pragma unroll
                    for (int q = 0; q < 4; ++q)
                        acc[q] += g2w[(k8 * 8 + i) * 32 + wv * 4 + q] * xk[i];
            }
            #pragma unroll
            for (int q = 0; q < 4; ++q) hp2[(wv * 4 + q) * 64 + lane] = acc[q];
        }
        __syncthreads();
        // ===== s2, d2 =====
        if (wv == 0) {
            float acc = 0.0f;
            #pragma unroll
            for (int o = 0; o < 32; ++o) acc += hp2[o * 64 + lane] * g2as[o];
            s2[lane] = acc;
        } else if (wv == 1) {
            float acc = 0.0f;
            #pragma unroll
            for (int o = 0; o < 32; ++o) acc += hp2[o * 64 + lane] * g2ad[o];
            d2[lane] = acc;
        }
        __syncthreads();
        // ===== attn2 -> gin =====
        {
            const float sv = s2[lane];
            float mx = -1e30f;
            #pragma unroll
            for (int m4 = 0; m4 < 16; ++m4) {
                float4 dv = *reinterpret_cast<const float4*>(&d2[m4 * 4]);
                mx = fmaxf(mx, leaky(sv + dv.x));
                mx = fmaxf(mx, leaky(sv + dv.y));
                mx = fmaxf(mx, leaky(sv + dv.z));
                mx = fmaxf(mx, leaky(sv + dv.w));
            }
            float sum = 0.0f;
            float acc[4];
            #pragma unroll
            for (int q = 0; q < 4; ++q) acc[q] = 0.0f;
            #pragma unroll
            for (int m4 = 0; m4 < 16; ++m4) {
                float4 dv = *reinterpret_cast<const float4*>(&d2[m4 * 4]);
                float e0 = __expf(leaky(sv + dv.x) - mx);
                float e1 = __expf(leaky(sv + dv.y) - mx);
                float e2 = __expf(leaky(sv + dv.z) - mx);
                float e3 = __expf(leaky(sv + dv.w) - mx);
                sum += e0 + e1 + e2 + e3;
                #pragma unroll
                for (int q = 0; q < 4; ++q) {
                    float4 hv = *reinterpret_cast<const float4*>(&hp2[(wv * 4 + q) * 64 + m4 * 4]);
                    acc[q] += e0 * hv.x + e1 * hv.y + e2 * hv.z + e3 * hv.w;
                }
            }
            float rs = 1.0f / sum;
            #pragma unroll
            for (int q = 0; q < 4; ++q)
                gin[(wv * 4 + q) * 64 + lane] = acc[q] * rs + g2b[wv * 4 + q];
        }
        __syncthreads();
        // ===== graph LSTM =====
        float ng[4];
        {
            float acc[16];
            #pragma unroll
            for (int ty = 0; ty < 4; ++ty)
                #pragma unroll
                for (int r = 0; r < 4; ++r) {
                    int gate = ty * 32 + wv * 4 + r;
                    acc[ty * 4 + r] = b_ih_g[gate] + b_hh_g[gate];
                }
            for (int k8 = 0; k8 < 4; ++k8) {
                float xk[8], hk[8];
                #pragma unroll
                for (int i = 0; i < 8; ++i) {
                    xk[i] = gin[(k8 * 8 + i) * 64 + lane];
                    hk[i] = s_gh[(k8 * 8 + i) * 64 + lane];
                }
                #pragma unroll
                for (int ty = 0; ty < 4; ++ty)
                    #pragma unroll
                    for (int r = 0; r < 4; ++r)
                        #pragma unroll
                        for (int i = 0; i < 8; ++i)
                            acc[ty * 4 + r] += w_ih_g[(ty * 32 + wv * 4 + r) * 32 + k8 * 8 + i] * xk[i]
                                             + w_hh_g[(ty * 32 + wv * 4 + r) * 32 + k8 * 8 + i] * hk[i];
            }
            #pragma unroll
            for (int r = 0; r < 4; ++r) {
                float c = sigf(acc[4 + r]) * cG[r] + sigf(acc[r]) * tanh_(acc[8 + r]);
                cG[r] = c;
                ng[r] = sigf(acc[12 + r]) * tanh_(c);
            }
        }
        __syncthreads();
        #pragma unroll
        for (int r = 0; r < 4; ++r) s_gh[(wv * 4 + r) * 64 + lane] = ng[r];
    } // t loop

    __syncthreads();   // fence final s_gh writes; encoder s_scr reads all complete

    // ======================= DECODER (MFMA) ================================
    // Apack: h (and px/bias) as bf16 hi/lo, [64 ped][AP k], k = 0..95
    u16* AhiA = (u16*)s_scr;
    u16* AloA = AhiA + 64 * AP;
    u16* AhiB = AloA + 64 * AP;
    u16* AloB = AhiB + 64 * AP;    // total 53248 B < 59904 B

    // ---- W fragments -> VGPRs. wave wv: nb = wv, wv+8, and 16+wv (wv<2). ----
    short8_t wfh[3][3], wfl[3][3];   // [slot][kb]
    {
        const int col = lane & 15, lb = lane >> 4;
        #pragma unroll
        for (int s = 0; s < 3; ++s) {
            if (s < 2 || wv < 2) {
                int nb = wv + 8 * s;
                int gp = nb * 16 + col;          // gate' = 4j+ty
                int j = gp >> 2, ty = gp & 3;
                int orig = ty * HP_ + j;
                #pragma unroll
                for (int kb = 0; kb < 3; ++kb) {
                    float vals[8];
                    int k0 = kb * 32 + lb * 8;
                    #pragma unroll
                    for (int jj = 0; jj < 8; ++jj) {
                        int k = k0 + jj;
                        float v;
                        if (k < 72)       v = w_hh_p[orig * HP_ + k];
                        else if (k == 72) v = w_ih_p[orig * 2 + 0];
                        else if (k == 73) v = w_ih_p[orig * 2 + 1];
                        else if (k == 74) v = b_ih_p[orig] + b_hh_p[orig];
                        else              v = 0.0f;
                        vals[jj] = v;
                    }
                    short8_t fh, fl;
                    #pragma unroll
                    for (int jj = 0; jj < 8; ++jj) {
                        u16 hb = bhi(vals[jj]);
                        float rem = vals[jj] - bf2f(hb);
                        fh[jj] = (short)hb;
                        fl[jj] = (short)bhi(rem);
                    }
                    wfh[s][kb] = fh;
                    wfl[s][kb] = fl;
                }
            }
        }
    }

    // ---- Apack init: k stride-8 per wave ----
    {
        float px0 = obs[(7 * NTOT + n) * 3 + 0];
        float px1 = obs[(7 * NTOT + n) * 3 + 1];
        #pragma unroll
        for (int kk = 0; kk < 12; ++kk) {
            int k = wv + kk * 8;
            float va, vb;
            if (k < 32)       { va = s_th[k * 64 + lane];        vb = 0.0f; }
            else if (k < 64)  { va = vb = s_gh[(k - 32) * 64 + lane]; }
            else if (k < 72)  { va = vb = zin[g * NZ_ + (k - 64)]; }
            else if (k == 72) { va = vb = px0; }
            else if (k == 73) { va = vb = px1; }
            else if (k == 74) { va = vb = 1.0f; }
            else              { va = vb = 0.0f; }
            u16 ha = bhi(va); u16 la = bhi(va - bf2f(ha));
            u16 hb = bhi(vb); u16 lb_ = bhi(vb - bf2f(hb));
            AhiA[lane * AP + k] = ha;  AloA[lane * AP + k] = la;
            AhiB[lane * AP + k] = hb;  AloB[lane * AP + k] = lb_;
        }
    }
    __syncthreads();

    float cstA[3][4], cstB[3][4];
    #pragma unroll
    for (int s = 0; s < 3; ++s)
        #pragma unroll
        for (int mb = 0; mb < 4; ++mb) { cstA[s][mb] = 0.0f; cstB[s][mb] = 0.0f; }

    const int lb2 = lane >> 4, u_ = (lane >> 2) & 3, t_ = lane & 3;
    const int pfrag = lane & 15, kgrp = (lane >> 4) * 8;

    for (int st = 0; st < FUT; ++st) {
        float h2A[3][4], h2B[3][4];
        // ---------------- cell A: GEMM + transpose + update ----------------
        {
            f32x4 acc[3][4];
            #pragma unroll
            for (int s = 0; s < 3; ++s)
                #pragma unroll
                for (int mb = 0; mb < 4; ++mb) acc[s][mb] = (f32x4){0.f, 0.f, 0.f, 0.f};
            #pragma unroll
            for (int kb = 0; kb < 3; ++kb) {
                short8_t ah[4], al[4];
                #pragma unroll
                for (int mb = 0; mb < 4; ++mb) {
                    int off = (mb * 16 + pfrag) * AP + kb * 32 + kgrp;
                    ah[mb] = *(const short8_t*)&AhiA[off];
                    al[mb] = *(const short8_t*)&AloA[off];
                }
                #pragma unroll
                for (int s = 0; s < 3; ++s) {
                    if (s < 2 || wv < 2) {
                        #pragma unroll
                        for (int mb = 0; mb < 4; ++mb) {
                            acc[s][mb] = __builtin_amdgcn_mfma_f32_16x16x32_bf16(ah[mb], wfh[s][kb], acc[s][mb], 0, 0, 0);
                            acc[s][mb] = __builtin_amdgcn_mfma_f32_16x16x32_bf16(ah[mb], wfl[s][kb], acc[s][mb], 0, 0, 0);
                            acc[s][mb] = __builtin_amdgcn_mfma_f32_16x16x32_bf16(al[mb], wfh[s][kb], acc[s][mb], 0, 0, 0);
                        }
                    }
                }
            }
            #pragma unroll
            for (int s = 0; s < 3; ++s)
                #pragma unroll
                for (int mb = 0; mb < 4; ++mb)
                    xpose_update(acc[s][mb], lane, cstA[s][mb], h2A[s][mb]);
        }
        // ---------------- cell B ----------------
        {
            f32x4 acc[3][4];
            #pragma unroll
            for (int s = 0; s < 3; ++s)
                #pragma unroll
                for (int mb = 0; mb < 4; ++mb) acc[s][mb] = (f32x4){0.f, 0.f, 0.f, 0.f};
            #pragma unroll
            for (int kb = 0; kb < 3; ++kb) {
                short8_t bh[4], bl[4];
                #pragma unroll
                for (int mb = 0; mb < 4; ++mb) {
                    int off = (mb * 16 + pfrag) * AP + kb * 32 + kgrp;
                    bh[mb] = *(const short8_t*)&AhiB[off];
                    bl[mb] = *(const short8_t*)&AloB[off];
                }
                #pragma unroll
                for (int s = 0; s < 3; ++s) {
                    if (s < 2 || wv < 2) {
                        #pragma unroll
                        for (int mb = 0; mb < 4; ++mb) {
                            acc[s][mb] = __builtin_amdgcn_mfma_f32_16x16x32_bf16(bh[mb], wfh[s][kb], acc[s][mb], 0, 0, 0);
                            acc[s][mb] = __builtin_amdgcn_mfma_f32_16x16x32_bf16(bh[mb], wfl[s][kb], acc[s][mb], 0, 0, 0);
                            acc[s][mb] = __builtin_amdgcn_mfma_f32_16x16x32_bf16(bl[mb], wfh[s][kb], acc[s][mb], 0, 0, 0);
                        }
                    }
                }
            }
            #pragma unroll
            for (int s = 0; s < 3; ++s)
                #pragma unroll
                for (int mb = 0; mb < 4; ++mb)
                    xpose_update(acc[s][mb], lane, cstB[s][mb], h2B[s][mb]);
        }
        __syncthreads();   // B1: all GEMM reads of Apack complete
        // ---- write h2 (bf16 hi/lo) back to Apack ----
        #pragma unroll
        for (int s = 0; s < 3; ++s) {
            if (s < 2 || wv < 2) {
                int nb = wv + 8 * s;
                int j = nb * 4 + u_;
                #pragma unroll
                for (int mb = 0; mb < 4; ++mb) {
                    int p = mb * 16 + lb2 * 4 + t_;
                    float va = h2A[s][mb];
                    float vb = h2B[s][mb];
                    u16 ha = bhi(va);
                    AhiA[p * AP + j] = ha;  AloA[p * AP + j] = bhi(va - bf2f(ha));
                    u16 hb = bhi(vb);
                    AhiB[p * AP + j] = hb;  AloB[p * AP + j] = bhi(vb - bf2f(hb));
                }
            }
        }
        __syncthreads();   // B2: h2 visible
        // ---- wave 0: output dot + px feedback ----
        if (wv == 0) {
            float s0 = 0.0f, s1_ = 0.0f;
            #pragma unroll
            for (int jb = 0; jb < 9; ++jb) {
                short8_t xha = *(const short8_t*)&AhiA[lane * AP + jb * 8];
                short8_t xla = *(const short8_t*)&AloA[lane * AP + jb * 8];
                short8_t xhb = *(const short8_t*)&AhiB[lane * AP + jb * 8];
                short8_t xlb = *(const short8_t*)&AloB[lane * AP + jb * 8];
                #pragma unroll
                for (int jj = 0; jj < 8; ++jj) {
                    int j = jb * 8 + jj;
                    float dh = (bf2f((u16)xha[jj]) + bf2f((u16)xla[jj]))
                             - (bf2f((u16)xhb[jj]) + bf2f((u16)xlb[jj]));
                    s0  += w_out[j] * dh;
                    s1_ += w_out[HP_ + j] * dh;
                }
            }
            float o0 = s0 + b_out[0], o1 = s1_ + b_out[1];
            *reinterpret_cast<float2*>(&out[(size_t)(st * NTOT + n) * 2]) = make_float2(o0, o1);
            u16 h0 = bhi(o0); u16 l0 = bhi(o0 - bf2f(h0));
            u16 h1 = bhi(o1); u16 l1 = bhi(o1 - bf2f(h1));
            AhiA[lane * AP + 72] = h0;  AloA[lane * AP + 72] = l0;
            AhiB[lane * AP + 72] = h0;  AloB[lane * AP + 72] = l0;
            AhiA[lane * AP + 73] = h1;  AloA[lane * AP + 73] = l1;
            AhiB[lane * AP + 73] = h1;  AloB[lane * AP + 73] = l1;
        }
        __syncthreads();   // B3: px visible for next step's GEMM
    }
}

extern "C" void kernel_launch(void* const* d_in, const int* in_sizes, int n_in,
                              void* d_out, int out_size, void* d_ws, size_t ws_size,
                              hipStream_t stream) {
    (void)in_sizes; (void)n_in; (void)out_size; (void)d_ws; (void)ws_size;
    stgat_fused<<<dim3(NGR), dim3(512), 0, stream>>>(
        (const float*)d_in[0],  (const float*)d_in[1],  (const float*)d_in[2],
        (const float*)d_in[3],  (const float*)d_in[4],  (const float*)d_in[5],
        (const float*)d_in[6],  (const float*)d_in[7],  (const float*)d_in[8],
        (const float*)d_in[9],  (const float*)d_in[10], (const float*)d_in[11],
        (const float*)d_in[12], (const float*)d_in[13], (const float*)d_in[14],
        (const float*)d_in[15], (const float*)d_in[16], (const float*)d_in[17],
        (const float*)d_in[18], (const float*)d_in[19], (const float*)d_in[20],
        (const float*)d_in[21], (const float*)d_in[22], (const float*)d_in[23],
        (const float*)d_in[24], (const float*)d_in[25], (const float*)d_in[26],
        (const float*)d_in[27],
        (float*)d_out);
}

// Round 5
// 1770.042 us; speedup vs baseline: 1.9720x; 1.0389x over previous
//
#include <hip/hip_runtime.h>

// STGAT round 5: split into encoder + decoder kernels.
//  - Encoder: VALU, LDS overlay shrunk to ~50.5KB -> 2 blocks/CU, VGPR capped 128.
//  - Decoder: MFMA bf16 hi/lo; W-lo fragments live in LDS (not VGPRs) to kill
//    round-4's register spills (377MB scratch writes). launch_bounds(512,1).
//  - Handoff: final traj_h / graph_h stored transposed [32][N] in d_ws.

#define OBS 8
#define FUT 12
#define NPED 64
#define HT_ 32
#define HG_ 32
#define NZ_ 8
#define HP_ 72
#define NGR 1024
#define NTOT (NGR * NPED)
#define AP 104   // Apack row stride in ushorts (208B, 16B-aligned; 2-way bank alias = free)

typedef __attribute__((ext_vector_type(8))) short short8_t;
typedef __attribute__((ext_vector_type(4))) float f32x4;
typedef unsigned short u16;

__device__ __forceinline__ float sigf(float x) { return 1.0f / (1.0f + __expf(-x)); }
__device__ __forceinline__ float tanh_(float x) {
    float e = __expf(2.0f * x);
    return 1.0f - 2.0f / (e + 1.0f);
}
__device__ __forceinline__ float leaky(float x) { return (x > 0.0f) ? x : 0.2f * x; }
__device__ __forceinline__ u16 bhi(float v) {              // round-to-nearest-even bf16
    unsigned u = __float_as_uint(v);
    return (u16)((u + 0x7FFFu + ((u >> 16) & 1u)) >> 16);
}
__device__ __forceinline__ float bf2f(u16 h) { return __uint_as_float(((unsigned)h) << 16); }

// ============================ ENCODER =====================================
__global__ __launch_bounds__(512, 2)
void stgat_enc(const float* __restrict__ obs,
               const float* __restrict__ traj_h0,
               const float* __restrict__ traj_c0,
               const float* __restrict__ graph_h0,
               const float* __restrict__ graph_c0,
               const float* __restrict__ w_ih_t,
               const float* __restrict__ w_hh_t,
               const float* __restrict__ b_ih_t,
               const float* __restrict__ b_hh_t,
               const float* __restrict__ g1w,
               const float* __restrict__ g1as,
               const float* __restrict__ g1ad,
               const float* __restrict__ g1b,
               const float* __restrict__ g2w,
               const float* __restrict__ g2as,
               const float* __restrict__ g2ad,
               const float* __restrict__ g2b,
               const float* __restrict__ w_ih_g,
               const float* __restrict__ w_hh_g,
               const float* __restrict__ b_ih_g,
               const float* __restrict__ b_hh_g,
               float* __restrict__ wsT,          // out: traj_h^T [32][N]
               float* __restrict__ wsG)          // out: graph_h^T [32][N]
{
    const int g    = blockIdx.x;
    const int lane = threadIdx.x & 63;
    const int wv   = __builtin_amdgcn_readfirstlane((int)(threadIdx.x >> 6));
    const int n    = g * NPED + lane;

    __shared__ float s_th[2048];
    __shared__ float s_gh[2048];
    __shared__ float scrA[4096];   // hp1 (4096) ; hp2 (first 2048)
    __shared__ float scrB[4096];   // xn (first 2048) ; x2 (4096) ; gin (first 2048)
    __shared__ float s1[256], d1[256], s2[64], d2[64];
    float* hp1 = scrA;
    float* hp2 = scrA;
    float* xn  = scrB;
    float* x2  = scrB;
    float* gin = scrB;

    float cT[4], cG[4];
    #pragma unroll
    for (int r = 0; r < 4; ++r) {
        int j = wv * 4 + r;
        s_th[j * 64 + lane] = traj_h0[n * HT_ + j];
        s_gh[j * 64 + lane] = graph_h0[n * HG_ + j];
        cT[r] = traj_c0[n * HT_ + j];
        cG[r] = graph_c0[n * HG_ + j];
    }
    __syncthreads();

    for (int t = 0; t < OBS; ++t) {
        // ===== traj LSTM (gates in regs) =====
        float nh[4];
        {
            const float x0 = obs[(t * NTOT + n) * 3 + 0];
            const float x1 = obs[(t * NTOT + n) * 3 + 1];
            const float xv = obs[(t * NTOT + n) * 3 + 2];
            float acc[16];
            #pragma unroll
            for (int ty = 0; ty < 4; ++ty)
                #pragma unroll
                for (int r = 0; r < 4; ++r) {
                    int gate = ty * 32 + wv * 4 + r;
                    acc[ty * 4 + r] = b_ih_t[gate] + b_hh_t[gate]
                                    + w_ih_t[gate * 3 + 0] * x0
                                    + w_ih_t[gate * 3 + 1] * x1
                                    + w_ih_t[gate * 3 + 2] * xv;
                }
            for (int k8 = 0; k8 < 4; ++k8) {
                float hk[8];
                #pragma unroll
                for (int i = 0; i < 8; ++i) hk[i] = s_th[(k8 * 8 + i) * 64 + lane];
                #pragma unroll
                for (int ty = 0; ty < 4; ++ty)
                    #pragma unroll
                    for (int r = 0; r < 4; ++r)
                        #pragma unroll
                        for (int i = 0; i < 8; ++i)
                            acc[ty * 4 + r] += w_hh_t[(ty * 32 + wv * 4 + r) * HT_ + k8 * 8 + i] * hk[i];
            }
            #pragma unroll
            for (int r = 0; r < 4; ++r) {
                float c = sigf(acc[4 + r]) * cT[r] + sigf(acc[r]) * tanh_(acc[8 + r]);
                cT[r] = c;
                nh[r] = sigf(acc[12 + r]) * tanh_(c);
            }
        }
        __syncthreads();                       // reads of old s_th done
        #pragma unroll
        for (int r = 0; r < 4; ++r) {
            int f = wv * 4 + r;
            s_th[f * 64 + lane] = nh[r];
            float v = nh[r];
            float sm = v, sq = v * v;
            #pragma unroll
            for (int m = 1; m < 64; m <<= 1) { sm += __shfl_xor(sm, m); sq += __shfl_xor(sq, m); }
            float mean = sm * (1.0f / 64.0f);
            float var  = sq * (1.0f / 64.0f) - mean * mean;
            xn[f * 64 + lane] = (v - mean) * rsqrtf(var + 1e-5f);
        }
        __syncthreads();
        // ===== GAT1 projection =====
        {
            const int h_ = wv >> 1;
            const int o0 = (wv & 1) * 8;
            float acc[8];
            #pragma unroll
            for (int q = 0; q < 8; ++q) acc[q] = 0.0f;
            for (int k8 = 0; k8 < 4; ++k8) {
                float xk[8];
                #pragma unroll
                for (int i = 0; i < 8; ++i) xk[i] = xn[(k8 * 8 + i) * 64 + lane];
                #pragma unroll
                for (int i = 0; i < 8; ++i)
                    #pragma unroll
                    for (int q = 0; q < 8; ++q)
                        acc[q] += g1w[h_ * 512 + (k8 * 8 + i) * 16 + o0 + q] * xk[i];
            }
            #pragma unroll
            for (int q = 0; q < 8; ++q) hp1[(h_ * 16 + o0 + q) * 64 + lane] = acc[q];
        }
        __syncthreads();
        // ===== s1, d1 =====
        {
            const int h_ = wv & 3;
            const float* av = (wv < 4) ? g1as : g1ad;
            float acc = 0.0f;
            #pragma unroll
            for (int o = 0; o < 16; ++o) acc += hp1[(h_ * 16 + o) * 64 + lane] * av[h_ * 16 + o];
            float* dst = (wv < 4) ? s1 : d1;
            dst[h_ * 64 + lane] = acc;
        }
        __syncthreads();
        // ===== attn1: two-pass + elu + fused inorm -> x2 =====
        {
            const int h_ = wv >> 1;
            const int o0 = (wv & 1) * 8;
            const float sv = s1[h_ * 64 + lane];
            float mx = -1e30f;
            #pragma unroll
            for (int m4 = 0; m4 < 16; ++m4) {
                float4 dv = *reinterpret_cast<const float4*>(&d1[h_ * 64 + m4 * 4]);
                mx = fmaxf(mx, leaky(sv + dv.x));
                mx = fmaxf(mx, leaky(sv + dv.y));
                mx = fmaxf(mx, leaky(sv + dv.z));
                mx = fmaxf(mx, leaky(sv + dv.w));
            }
            float sum = 0.0f;
            float acc[8];
            #pragma unroll
            for (int q = 0; q < 8; ++q) acc[q] = 0.0f;
            #pragma unroll
            for (int m4 = 0; m4 < 16; ++m4) {
                float4 dv = *reinterpret_cast<const float4*>(&d1[h_ * 64 + m4 * 4]);
                float e0 = __expf(leaky(sv + dv.x) - mx);
                float e1 = __expf(leaky(sv + dv.y) - mx);
                float e2 = __expf(leaky(sv + dv.z) - mx);
                float e3 = __expf(leaky(sv + dv.w) - mx);
                sum += e0 + e1 + e2 + e3;
                #pragma unroll
                for (int q = 0; q < 8; ++q) {
                    float4 hv = *reinterpret_cast<const float4*>(&hp1[(h_ * 16 + o0 + q) * 64 + m4 * 4]);
                    acc[q] += e0 * hv.x + e1 * hv.y + e2 * hv.z + e3 * hv.w;
                }
            }
            float rs = 1.0f / sum;
            #pragma unroll
            for (int q = 0; q < 8; ++q) {
                float v = acc[q] * rs + g1b[o0 + q];
                v = (v > 0.0f) ? v : (__expf(v) - 1.0f);
                float sm = v, sq = v * v;
                #pragma unroll
                for (int m = 1; m < 64; m <<= 1) { sm += __shfl_xor(sm, m); sq += __shfl_xor(sq, m); }
                float mean = sm * (1.0f / 64.0f);
                float var  = sq * (1.0f / 64.0f) - mean * mean;
                x2[(h_ * 16 + o0 + q) * 64 + lane] = (v - mean) * rsqrtf(var + 1e-5f);
            }
        }
        __syncthreads();
        // ===== GAT2 projection (reads x2=scrB, writes hp2=scrA[0:2048]) =====
        {
            float acc[4];
            #pragma unroll
            for (int q = 0; q < 4; ++q) acc[q] = 0.0f;
            for (int k8 = 0; k8 < 8; ++k8) {
                float xk[8];
                #pragma unroll
                for (int i = 0; i < 8; ++i) xk[i] = x2[(k8 * 8 + i) * 64 + lane];
                #pragma unroll
                for (int i = 0; i < 8; ++i)
                    #pragma unroll
                    for (int q = 0; q < 4; ++q)
                        acc[q] += g2w[(k8 * 8 + i) * 32 + wv * 4 + q] * xk[i];
            }
            #pragma unroll
            for (int q = 0; q < 4; ++q) hp2[(wv * 4 + q) * 64 + lane] = acc[q];
        }
        __syncthreads();
        // ===== s2, d2 =====
        if (wv == 0) {
            float acc = 0.0f;
            #pragma unroll
            for (int o = 0; o < 32; ++o) acc += hp2[o * 64 + lane] * g2as[o];
            s2[lane] = acc;
        } else if (wv == 1) {
            float acc = 0.0f;
            #pragma unroll
            for (int o = 0; o < 32; ++o) acc += hp2[o * 64 + lane] * g2ad[o];
            d2[lane] = acc;
        }
        __syncthreads();
        // ===== attn2 -> gin (scrB[0:2048], x2 dead) =====
        {
            const float sv = s2[lane];
            float mx = -1e30f;
            #pragma unroll
            for (int m4 = 0; m4 < 16; ++m4) {
                float4 dv = *reinterpret_cast<const float4*>(&d2[m4 * 4]);
                mx = fmaxf(mx, leaky(sv + dv.x));
                mx = fmaxf(mx, leaky(sv + dv.y));
                mx = fmaxf(mx, leaky(sv + dv.z));
                mx = fmaxf(mx, leaky(sv + dv.w));
            }
            float sum = 0.0f;
            float acc[4];
            #pragma unroll
            for (int q = 0; q < 4; ++q) acc[q] = 0.0f;
            #pragma unroll
            for (int m4 = 0; m4 < 16; ++m4) {
                float4 dv = *reinterpret_cast<const float4*>(&d2[m4 * 4]);
                float e0 = __expf(leaky(sv + dv.x) - mx);
                float e1 = __expf(leaky(sv + dv.y) - mx);
                float e2 = __expf(leaky(sv + dv.z) - mx);
                float e3 = __expf(leaky(sv + dv.w) - mx);
                sum += e0 + e1 + e2 + e3;
                #pragma unroll
                for (int q = 0; q < 4; ++q) {
                    float4 hv = *reinterpret_cast<const float4*>(&hp2[(wv * 4 + q) * 64 + m4 * 4]);
                    acc[q] += e0 * hv.x + e1 * hv.y + e2 * hv.z + e3 * hv.w;
                }
            }
            float rs = 1.0f / sum;
            #pragma unroll
            for (int q = 0; q < 4; ++q)
                gin[(wv * 4 + q) * 64 + lane] = acc[q] * rs + g2b[wv * 4 + q];
        }
        __syncthreads();
        // ===== graph LSTM =====
        float ng[4];
        {
            float acc[16];
            #pragma unroll
            for (int ty = 0; ty < 4; ++ty)
                #pragma unroll
                for (int r = 0; r < 4; ++r) {
                    int gate = ty * 32 + wv * 4 + r;
                    acc[ty * 4 + r] = b_ih_g[gate] + b_hh_g[gate];
                }
            for (int k8 = 0; k8 < 4; ++k8) {
                float xk[8], hk[8];
                #pragma unroll
                for (int i = 0; i < 8; ++i) {
                    xk[i] = gin[(k8 * 8 + i) * 64 + lane];
                    hk[i] = s_gh[(k8 * 8 + i) * 64 + lane];
                }
                #pragma unroll
                for (int ty = 0; ty < 4; ++ty)
                    #pragma unroll
                    for (int r = 0; r < 4; ++r)
                        #pragma unroll
                        for (int i = 0; i < 8; ++i)
                            acc[ty * 4 + r] += w_ih_g[(ty * 32 + wv * 4 + r) * 32 + k8 * 8 + i] * xk[i]
                                             + w_hh_g[(ty * 32 + wv * 4 + r) * 32 + k8 * 8 + i] * hk[i];
            }
            #pragma unroll
            for (int r = 0; r < 4; ++r) {
                float c = sigf(acc[4 + r]) * cG[r] + sigf(acc[r]) * tanh_(acc[8 + r]);
                cG[r] = c;
                ng[r] = sigf(acc[12 + r]) * tanh_(c);
            }
        }
        __syncthreads();
        #pragma unroll
        for (int r = 0; r < 4; ++r) s_gh[(wv * 4 + r) * 64 + lane] = ng[r];
    } // t loop

    __syncthreads();
    // ---- hand off final states (transposed: coalesced write AND read) ----
    #pragma unroll
    for (int r = 0; r < 4; ++r) {
        int j = wv * 4 + r;
        wsT[j * NTOT + n] = s_th[j * 64 + lane];
        wsG[j * NTOT + n] = s_gh[j * 64 + lane];
    }
}

// ============================ DECODER =====================================
// 4x4 transpose across 4-lane group x 4 regs, then LSTM pointwise update.
__device__ __forceinline__ void xpose_update(f32x4 acc, int lane, float& cstate, float& h2out) {
    float v0 = acc[0], v1 = acc[1], v2 = acc[2], v3 = acc[3];
    float s0 = __shfl_xor(v0, 1), s1 = __shfl_xor(v1, 1);
    float s2 = __shfl_xor(v2, 1), s3 = __shfl_xor(v3, 1);
    bool b0 = (lane & 1);
    float u0 = b0 ? s1 : v0;
    float u1 = b0 ? v1 : s0;
    float u2 = b0 ? s3 : v2;
    float u3 = b0 ? v3 : s2;
    float t0 = __shfl_xor(u0, 2), t1 = __shfl_xor(u1, 2);
    float t2 = __shfl_xor(u2, 2), t3 = __shfl_xor(u3, 2);
    bool b1 = (lane & 2);
    float w0 = b1 ? t2 : u0;   // i
    float w1 = b1 ? t3 : u1;   // f
    float w2 = b1 ? u2 : t0;   // g
    float w3 = b1 ? u3 : t1;   // o
    float c2 = sigf(w1) * cstate + sigf(w0) * tanh_(w2);
    cstate = c2;
    h2out = sigf(w3) * tanh_(c2);
}

__global__ __launch_bounds__(512, 1)
void stgat_dec(const float* __restrict__ obs,
               const float* __restrict__ zin,
               const float* __restrict__ w_ih_p,
               const float* __restrict__ w_hh_p,
               const float* __restrict__ b_ih_p,
               const float* __restrict__ b_hh_p,
               const float* __restrict__ w_out,
               const float* __restrict__ b_out,
               const float* __restrict__ wsT,    // traj_h^T [32][N]
               const float* __restrict__ wsG,    // graph_h^T [32][N]
               float* __restrict__ out)
{
    const int g    = blockIdx.x;
    const int lane = threadIdx.x & 63;
    const int wv   = __builtin_amdgcn_readfirstlane((int)(threadIdx.x >> 6));
    const int n    = g * NPED + lane;

    __shared__ u16      Apack[4 * 64 * AP];   // AhiA | AloA | AhiB | AloB, 53248 B
    __shared__ short8_t WloS[18 * 3 * 64];    // W low-half fragments, 55296 B
    u16* AhiA = Apack;
    u16* AloA = AhiA + 64 * AP;
    u16* AhiB = AloA + 64 * AP;
    u16* AloB = AhiB + 64 * AP;

    // ---- W fragments: hi -> VGPR (wave-owned), lo -> LDS ----
    short8_t wfh[3][3];   // [slot][kb], slot 2 valid only for wv<2
    {
        const int col = lane & 15, lb = lane >> 4;
        #pragma unroll
        for (int s = 0; s < 3; ++s) {
            if (s < 2 || wv < 2) {
                int nb = wv + 8 * s;
                int gp = nb * 16 + col;          // gate' = 4j+ty
                int j = gp >> 2, ty = gp & 3;
                int orig = ty * HP_ + j;
                #pragma unroll
                for (int kb = 0; kb < 3; ++kb) {
                    short8_t fh, fl;
                    #pragma unroll
                    for (int jj = 0; jj < 8; ++jj) {
                        int k = kb * 32 + lb * 8 + jj;
                        float v;
                        if (k < 72)       v = w_hh_p[orig * HP_ + k];
                        else if (k == 72) v = w_ih_p[orig * 2 + 0];
                        else if (k == 73) v = w_ih_p[orig * 2 + 1];
                        else if (k == 74) v = b_ih_p[orig] + b_hh_p[orig];
                        else              v = 0.0f;
                        u16 hb = bhi(v);
                        fh[jj] = (short)hb;
                        fl[jj] = (short)bhi(v - bf2f(hb));
                    }
                    wfh[s][kb] = fh;
                    WloS[(nb * 3 + kb) * 64 + lane] = fl;
                }
            }
        }
    }

    // ---- Apack init ----
    {
        float px0 = obs[(7 * NTOT + n) * 3 + 0];
        float px1 = obs[(7 * NTOT + n) * 3 + 1];
        #pragma unroll
        for (int kk = 0; kk < 12; ++kk) {
            int k = wv + kk * 8;
            float va, vb;
            if (k < 32)       { va = wsT[k * NTOT + n];            vb = 0.0f; }
            else if (k < 64)  { va = vb = wsG[(k - 32) * NTOT + n]; }
            else if (k < 72)  { va = vb = zin[g * NZ_ + (k - 64)]; }
            else if (k == 72) { va = vb = px0; }
            else if (k == 73) { va = vb = px1; }
            else if (k == 74) { va = vb = 1.0f; }
            else              { va = vb = 0.0f; }
            u16 ha = bhi(va); u16 la = bhi(va - bf2f(ha));
            u16 hb = bhi(vb); u16 lb_ = bhi(vb - bf2f(hb));
            AhiA[lane * AP + k] = ha;  AloA[lane * AP + k] = la;
            AhiB[lane * AP + k] = hb;  AloB[lane * AP + k] = lb_;
        }
    }
    __syncthreads();

    float cstA[3][4], cstB[3][4];
    #pragma unroll
    for (int s = 0; s < 3; ++s)
        #pragma unroll
        for (int mb = 0; mb < 4; ++mb) { cstA[s][mb] = 0.0f; cstB[s][mb] = 0.0f; }

    const int lb2 = lane >> 4, u_ = (lane >> 2) & 3, t_ = lane & 3;
    const int pfrag = lane & 15, kgrp = (lane >> 4) * 8;

    for (int st = 0; st < FUT; ++st) {
        float h2A[3][4], h2B[3][4];
        // ---------------- cell A ----------------
        {
            f32x4 acc[3][4];
            #pragma unroll
            for (int s = 0; s < 3; ++s)
                #pragma unroll
                for (int mb = 0; mb < 4; ++mb) acc[s][mb] = (f32x4){0.f, 0.f, 0.f, 0.f};
            #pragma unroll
            for (int kb = 0; kb < 3; ++kb) {
                short8_t ah[4], al[4];
                #pragma unroll
                for (int mb = 0; mb < 4; ++mb) {
                    int off = (mb * 16 + pfrag) * AP + kb * 32 + kgrp;
                    ah[mb] = *(const short8_t*)&AhiA[off];
                    al[mb] = *(const short8_t*)&AloA[off];
                }
                #pragma unroll
                for (int s = 0; s < 3; ++s) {
                    if (s < 2 || wv < 2) {
                        int nb = wv + 8 * s;
                        short8_t wl = WloS[(nb * 3 + kb) * 64 + lane];
                        #pragma unroll
                        for (int mb = 0; mb < 4; ++mb) {
                            acc[s][mb] = __builtin_amdgcn_mfma_f32_16x16x32_bf16(ah[mb], wfh[s][kb], acc[s][mb], 0, 0, 0);
                            acc[s][mb] = __builtin_amdgcn_mfma_f32_16x16x32_bf16(ah[mb], wl,         acc[s][mb], 0, 0, 0);
                            acc[s][mb] = __builtin_amdgcn_mfma_f32_16x16x32_bf16(al[mb], wfh[s][kb], acc[s][mb], 0, 0, 0);
                        }
                    }
                }
            }
            #pragma unroll
            for (int s = 0; s < 3; ++s)
                #pragma unroll
                for (int mb = 0; mb < 4; ++mb)
                    xpose_update(acc[s][mb], lane, cstA[s][mb], h2A[s][mb]);
        }
        // ---------------- cell B ----------------
        {
            f32x4 acc[3][4];
            #pragma unroll
            for (int s = 0; s < 3; ++s)
                #pragma unroll
                for (int mb = 0; mb < 4; ++mb) acc[s][mb] = (f32x4){0.f, 0.f, 0.f, 0.f};
            #pragma unroll
            for (int kb = 0; kb < 3; ++kb) {
                short8_t bh[4], bl[4];
                #pragma unroll
                for (int mb = 0; mb < 4; ++mb) {
                    int off = (mb * 16 + pfrag) * AP + kb * 32 + kgrp;
                    bh[mb] = *(const short8_t*)&AhiB[off];
                    bl[mb] = *(const short8_t*)&AloB[off];
                }
                #pragma unroll
                for (int s = 0; s < 3; ++s) {
                    if (s < 2 || wv < 2) {
                        int nb = wv + 8 * s;
                        short8_t wl = WloS[(nb * 3 + kb) * 64 + lane];
                        #pragma unroll
                        for (int mb = 0; mb < 4; ++mb) {
                            acc[s][mb] = __builtin_amdgcn_mfma_f32_16x16x32_bf16(bh[mb], wfh[s][kb], acc[s][mb], 0, 0, 0);
                            acc[s][mb] = __builtin_amdgcn_mfma_f32_16x16x32_bf16(bh[mb], wl,         acc[s][mb], 0, 0, 0);
                            acc[s][mb] = __builtin_amdgcn_mfma_f32_16x16x32_bf16(bl[mb], wfh[s][kb], acc[s][mb], 0, 0, 0);
                        }
                    }
                }
            }
            #pragma unroll
            for (int s = 0; s < 3; ++s)
                #pragma unroll
                for (int mb = 0; mb < 4; ++mb)
                    xpose_update(acc[s][mb], lane, cstB[s][mb], h2B[s][mb]);
        }
        __syncthreads();   // B1: all GEMM reads of Apack complete
        // ---- write h2 (bf16 hi/lo) back to Apack ----
        #pragma unroll
        for (int s = 0; s < 3; ++s) {
            if (s < 2 || wv < 2) {
                int nb = wv + 8 * s;
                int j = nb * 4 + u_;
                #pragma unroll
                for (int mb = 0; mb < 4; ++mb) {
                    int p = mb * 16 + lb2 * 4 + t_;
                    float va = h2A[s][mb];
                    float vb = h2B[s][mb];
                    u16 ha = bhi(va);
                    AhiA[p * AP + j] = ha;  AloA[p * AP + j] = bhi(va - bf2f(ha));
                    u16 hb = bhi(vb);
                    AhiB[p * AP + j] = hb;  AloB[p * AP + j] = bhi(vb - bf2f(hb));
                }
            }
        }
        __syncthreads();   // B2: h2 visible
        // ---- wave 0: output dot + px feedback ----
        if (wv == 0) {
            float s0 = 0.0f, s1_ = 0.0f;
            #pragma unroll
            for (int jb = 0; jb < 9; ++jb) {
                short8_t xha = *(const short8_t*)&AhiA[lane * AP + jb * 8];
                short8_t xla = *(const short8_t*)&AloA[lane * AP + jb * 8];
                short8_t xhb = *(const short8_t*)&AhiB[lane * AP + jb * 8];
                short8_t xlb = *(const short8_t*)&AloB[lane * AP + jb * 8];
                #pragma unroll
                for (int jj = 0; jj < 8; ++jj) {
                    int j = jb * 8 + jj;
                    float dh = (bf2f((u16)xha[jj]) + bf2f((u16)xla[jj]))
                             - (bf2f((u16)xhb[jj]) + bf2f((u16)xlb[jj]));
                    s0  += w_out[j] * dh;
                    s1_ += w_out[HP_ + j] * dh;
                }
            }
            float o0 = s0 + b_out[0], o1 = s1_ + b_out[1];
            *reinterpret_cast<float2*>(&out[(size_t)(st * NTOT + n) * 2]) = make_float2(o0, o1);
            u16 h0 = bhi(o0); u16 l0 = bhi(o0 - bf2f(h0));
            u16 h1 = bhi(o1); u16 l1 = bhi(o1 - bf2f(h1));
            AhiA[lane * AP + 72] = h0;  AloA[lane * AP + 72] = l0;
            AhiB[lane * AP + 72] = h0;  AloB[lane * AP + 72] = l0;
            AhiA[lane * AP + 73] = h1;  AloA[lane * AP + 73] = l1;
            AhiB[lane * AP + 73] = h1;  AloB[lane * AP + 73] = l1;
        }
        __syncthreads();   // B3: px visible for next step
    }
}

extern "C" void kernel_launch(void* const* d_in, const int* in_sizes, int n_in,
                              void* d_out, int out_size, void* d_ws, size_t ws_size,
                              hipStream_t stream) {
    (void)in_sizes; (void)n_in; (void)out_size; (void)ws_size;
    float* wsT = (float*)d_ws;                 // [32][N]
    float* wsG = wsT + (size_t)HT_ * NTOT;     // [32][N]  (total 16.8 MB)

    stgat_enc<<<dim3(NGR), dim3(512), 0, stream>>>(
        (const float*)d_in[0],                        // obs
        (const float*)d_in[2],  (const float*)d_in[3],  // traj h0/c0
        (const float*)d_in[4],  (const float*)d_in[5],  // graph h0/c0
        (const float*)d_in[6],  (const float*)d_in[7],  (const float*)d_in[8],  (const float*)d_in[9],
        (const float*)d_in[10], (const float*)d_in[11], (const float*)d_in[12], (const float*)d_in[13],
        (const float*)d_in[14], (const float*)d_in[15], (const float*)d_in[16], (const float*)d_in[17],
        (const float*)d_in[18], (const float*)d_in[19], (const float*)d_in[20], (const float*)d_in[21],
        wsT, wsG);

    stgat_dec<<<dim3(NGR), dim3(512), 0, stream>>>(
        (const float*)d_in[0],                        // obs
        (const float*)d_in[1],                        // z
        (const float*)d_in[22], (const float*)d_in[23], // w_ih_p, w_hh_p
        (const float*)d_in[24], (const float*)d_in[25], // b_ih_p, b_hh_p
        (const float*)d_in[26], (const float*)d_in[27], // w_out, b_out
        wsT, wsG,
        (float*)d_out);
}

// Round 6
// 1510.528 us; speedup vs baseline: 2.3108x; 1.1718x over previous
//
#include <hip/hip_runtime.h>

// STGAT round 6: encoder LSTMs moved to MFMA (decoder-pattern: gate'=4j+ty,
// bf16 hi/lo A-pack in LDS, W frags in VGPRs, 4x4 shuffle-transpose epilogue).
// Single-pass softmax (no max), s/d partials fused into projection phases.
// Decoder identical to round 5 (known-good).

#define OBS 8
#define FUT 12
#define NPED 64
#define HT_ 32
#define HG_ 32
#define NZ_ 8
#define HP_ 72
#define NGR 1024
#define NTOT (NGR * NPED)
#define AP 104    // decoder A stride (u16)
#define EAP 72    // encoder A stride (u16): 144B rows -> 2-way bank alias (free)

typedef __attribute__((ext_vector_type(8))) short short8_t;
typedef __attribute__((ext_vector_type(4))) float f32x4;
typedef unsigned short u16;

__device__ __forceinline__ float sigf(float x) { return 1.0f / (1.0f + __expf(-x)); }
__device__ __forceinline__ float tanh_(float x) {
    float e = __expf(2.0f * x);
    return 1.0f - 2.0f / (e + 1.0f);
}
__device__ __forceinline__ float leaky(float x) { return (x > 0.0f) ? x : 0.2f * x; }
__device__ __forceinline__ u16 bhi(float v) {              // round-to-nearest-even bf16
    unsigned u = __float_as_uint(v);
    return (u16)((u + 0x7FFFu + ((u >> 16) & 1u)) >> 16);
}
__device__ __forceinline__ float bf2f(u16 h) { return __uint_as_float(((unsigned)h) << 16); }

// 4x4 transpose across 4-lane group x 4 regs, add gate biases, LSTM pointwise.
__device__ __forceinline__ void xpose_update(f32x4 acc, int lane,
                                             float bI, float bF, float bG, float bO,
                                             float& cstate, float& h2out) {
    float v0 = acc[0], v1 = acc[1], v2 = acc[2], v3 = acc[3];
    float s0 = __shfl_xor(v0, 1), s1 = __shfl_xor(v1, 1);
    float s2 = __shfl_xor(v2, 1), s3 = __shfl_xor(v3, 1);
    bool b0 = (lane & 1);
    float u0 = b0 ? s1 : v0;
    float u1 = b0 ? v1 : s0;
    float u2 = b0 ? s3 : v2;
    float u3 = b0 ? v3 : s2;
    float t0 = __shfl_xor(u0, 2), t1 = __shfl_xor(u1, 2);
    float t2 = __shfl_xor(u2, 2), t3 = __shfl_xor(u3, 2);
    bool b1 = (lane & 2);
    float w0 = (b1 ? t2 : u0) + bI;   // i
    float w1 = (b1 ? t3 : u1) + bF;   // f
    float w2 = (b1 ? u2 : t0) + bG;   // g
    float w3 = (b1 ? u3 : t1) + bO;   // o
    float c2 = sigf(w1) * cstate + sigf(w0) * tanh_(w2);
    cstate = c2;
    h2out = sigf(w3) * tanh_(c2);
}

// ============================ ENCODER =====================================
__global__ __launch_bounds__(512, 2)
void stgat_enc(const float* __restrict__ obs,
               const float* __restrict__ traj_h0,
               const float* __restrict__ traj_c0,
               const float* __restrict__ graph_h0,
               const float* __restrict__ graph_c0,
               const float* __restrict__ w_ih_t,
               const float* __restrict__ w_hh_t,
               const float* __restrict__ b_ih_t,
               const float* __restrict__ b_hh_t,
               const float* __restrict__ g1w,
               const float* __restrict__ g1as,
               const float* __restrict__ g1ad,
               const float* __restrict__ g1b,
               const float* __restrict__ g2w,
               const float* __restrict__ g2as,
               const float* __restrict__ g2ad,
               const float* __restrict__ g2b,
               const float* __restrict__ w_ih_g,
               const float* __restrict__ w_hh_g,
               const float* __restrict__ b_ih_g,
               const float* __restrict__ b_hh_g,
               float* __restrict__ wsT,          // out: traj_h^T [32][N]
               float* __restrict__ wsG)          // out: graph_h^T [32][N]
{
    const int g    = blockIdx.x;
    const int lane = threadIdx.x & 63;
    const int wv   = __builtin_amdgcn_readfirstlane((int)(threadIdx.x >> 6));
    const int n    = g * NPED + lane;

    __shared__ __attribute__((aligned(16))) u16 ATh[64 * EAP], ATl[64 * EAP]; // traj A (18432 B)
    __shared__ __attribute__((aligned(16))) u16 AGh[64 * EAP], AGl[64 * EAP]; // graph A (18432 B)
    __shared__ float hp1s[4096];   // 16 KB; hp2 overlays first 2048
    __shared__ float scrB2[4096];  // xn = first 2048; x2 = full
    __shared__ float sp1s[512], dp1s[512];  // [half*4+h][64]
    __shared__ float sp2s[512], dp2s[512];  // [w][64]
    __shared__ float biasg[128];
    float* hp2 = hp1s;
    float* xn  = scrB2;
    float* x2  = scrB2;

    const int pfrag = lane & 15, kg8 = (lane >> 4) * 8;
    const int lb2 = lane >> 4, u2 = (lane >> 2) & 3, t_ = lane & 3;
    const int j2 = wv * 4 + u2;      // feature/j owned after transpose

    // ---- W fragments (VGPR-persistent) ----
    short8_t wfhT[2], wflT[2], wfhG[2], wflG[2];
    {
        int gp = wv * 16 + pfrag, j = gp >> 2, ty = gp & 3, orig = ty * 32 + j;
        #pragma unroll
        for (int kb = 0; kb < 2; ++kb) {
            short8_t fhT, flT, fhG, flG;
            #pragma unroll
            for (int jj = 0; jj < 8; ++jj) {
                int k = kb * 32 + (lane >> 4) * 8 + jj;
                float vT, vG;
                if (k < 32)       vT = w_hh_t[orig * 32 + k];
                else if (k < 35)  vT = w_ih_t[orig * 3 + (k - 32)];
                else if (k == 35) vT = b_ih_t[orig] + b_hh_t[orig];
                else              vT = 0.0f;
                if (k < 32)       vG = w_ih_g[orig * 32 + k];
                else              vG = w_hh_g[orig * 32 + (k - 32)];
                u16 hT = bhi(vT); fhT[jj] = (short)hT; flT[jj] = (short)bhi(vT - bf2f(hT));
                u16 hG = bhi(vG); fhG[jj] = (short)hG; flG[jj] = (short)bhi(vG - bf2f(hG));
            }
            wfhT[kb] = fhT; wflT[kb] = flT;
            wfhG[kb] = fhG; wflG[kb] = flG;
        }
    }

    // ---- init A-packs, c-states, bias table ----
    #pragma unroll
    for (int r = 0; r < 4; ++r) {
        int j = wv * 4 + r;
        float vt = traj_h0[n * HT_ + j];
        u16 ht = bhi(vt);
        ATh[lane * EAP + j] = ht;  ATl[lane * EAP + j] = bhi(vt - bf2f(ht));
        float vg = graph_h0[n * HG_ + j];
        u16 hg = bhi(vg);
        AGh[lane * EAP + 32 + j] = hg;  AGl[lane * EAP + 32 + j] = bhi(vg - bf2f(hg));
    }
    float cT2[4], cG2[4];
    #pragma unroll
    for (int mb = 0; mb < 4; ++mb) {
        int p = mb * 16 + lb2 * 4 + t_;
        cT2[mb] = traj_c0[(g * 64 + p) * HT_ + j2];
        cG2[mb] = graph_c0[(g * 64 + p) * HG_ + j2];
    }
    if (wv == 0) {        // x(0) + const-1 col
        #pragma unroll
        for (int c = 0; c < 3; ++c) {
            float v = obs[(0 * NTOT + n) * 3 + c];
            u16 h = bhi(v);
            ATh[lane * EAP + 32 + c] = h;  ATl[lane * EAP + 32 + c] = bhi(v - bf2f(h));
        }
        ATh[lane * EAP + 35] = 0x3F80;  ATl[lane * EAP + 35] = 0;
    } else if (wv == 1) { // zero pad cols 36..63 (avoid NaN garbage in MFMA)
        for (int c = 36; c < 64; ++c) { ATh[lane * EAP + c] = 0; ATl[lane * EAP + c] = 0; }
    }
    if (threadIdx.x < 128) biasg[threadIdx.x] = b_ih_g[threadIdx.x] + b_hh_g[threadIdx.x];
    __syncthreads();

    for (int t = 0; t < OBS; ++t) {
        // ===== T1: traj LSTM via MFMA =====
        float h2T[4], xnv[4];
        {
            f32x4 acc[4];
            #pragma unroll
            for (int mb = 0; mb < 4; ++mb) acc[mb] = (f32x4){0.f, 0.f, 0.f, 0.f};
            #pragma unroll
            for (int kb = 0; kb < 2; ++kb) {
                short8_t ah[4], al[4];
                #pragma unroll
                for (int mb = 0; mb < 4; ++mb) {
                    int off = (mb * 16 + pfrag) * EAP + kb * 32 + kg8;
                    ah[mb] = *(const short8_t*)&ATh[off];
                    al[mb] = *(const short8_t*)&ATl[off];
                }
                #pragma unroll
                for (int mb = 0; mb < 4; ++mb) {
                    acc[mb] = __builtin_amdgcn_mfma_f32_16x16x32_bf16(ah[mb], wfhT[kb], acc[mb], 0, 0, 0);
                    acc[mb] = __builtin_amdgcn_mfma_f32_16x16x32_bf16(ah[mb], wflT[kb], acc[mb], 0, 0, 0);
                    acc[mb] = __builtin_amdgcn_mfma_f32_16x16x32_bf16(al[mb], wfhT[kb], acc[mb], 0, 0, 0);
                }
            }
            #pragma unroll
            for (int mb = 0; mb < 4; ++mb)
                xpose_update(acc[mb], lane, 0.f, 0.f, 0.f, 0.f, cT2[mb], h2T[mb]);
            // inorm over 64 peds for feature j2 (lanes vary bits 0,1,4,5 + mb)
            float sm = h2T[0] + h2T[1] + h2T[2] + h2T[3];
            float sq = h2T[0]*h2T[0] + h2T[1]*h2T[1] + h2T[2]*h2T[2] + h2T[3]*h2T[3];
            sm += __shfl_xor(sm, 1);  sq += __shfl_xor(sq, 1);
            sm += __shfl_xor(sm, 2);  sq += __shfl_xor(sq, 2);
            sm += __shfl_xor(sm, 16); sq += __shfl_xor(sq, 16);
            sm += __shfl_xor(sm, 32); sq += __shfl_xor(sq, 32);
            float mean = sm * (1.0f / 64.0f);
            float var  = sq * (1.0f / 64.0f) - mean * mean;
            float rstd = rsqrtf(var + 1e-5f);
            #pragma unroll
            for (int mb = 0; mb < 4; ++mb) xnv[mb] = (h2T[mb] - mean) * rstd;
        }
        __syncthreads();   // B1: all MFMA reads of AT done
        // ===== T2: write-back h2 + xn; wave0 stages x(t+1) =====
        #pragma unroll
        for (int mb = 0; mb < 4; ++mb) {
            int p = mb * 16 + lb2 * 4 + t_;
            u16 h = bhi(h2T[mb]);
            ATh[p * EAP + j2] = h;  ATl[p * EAP + j2] = bhi(h2T[mb] - bf2f(h));
            xn[j2 * 64 + p] = xnv[mb];
        }
        if (t == OBS - 1) {
            #pragma unroll
            for (int mb = 0; mb < 4; ++mb) {
                int p = mb * 16 + lb2 * 4 + t_;
                wsT[j2 * NTOT + g * 64 + p] = h2T[mb];
            }
        }
        if (wv == 0 && t < OBS - 1) {
            #pragma unroll
            for (int c = 0; c < 3; ++c) {
                float v = obs[((t + 1) * NTOT + n) * 3 + c];
                u16 h = bhi(v);
                ATh[lane * EAP + 32 + c] = h;  ATl[lane * EAP + 32 + c] = bhi(v - bf2f(h));
            }
        }
        __syncthreads();   // B2: xn visible
        // ===== G1: GAT1 projection + s/d partials =====
        {
            const int h_ = wv >> 1;
            const int o0 = (wv & 1) * 8;
            float acc[8];
            #pragma unroll
            for (int q = 0; q < 8; ++q) acc[q] = 0.0f;
            for (int k8 = 0; k8 < 4; ++k8) {
                float xk[8];
                #pragma unroll
                for (int i = 0; i < 8; ++i) xk[i] = xn[(k8 * 8 + i) * 64 + lane];
                #pragma unroll
                for (int i = 0; i < 8; ++i)
                    #pragma unroll
                    for (int q = 0; q < 8; ++q)
                        acc[q] += g1w[h_ * 512 + (k8 * 8 + i) * 16 + o0 + q] * xk[i];
            }
            float ps = 0.0f, pd = 0.0f;
            #pragma unroll
            for (int q = 0; q < 8; ++q) {
                hp1s[(h_ * 16 + o0 + q) * 64 + lane] = acc[q];
                ps += acc[q] * g1as[h_ * 16 + o0 + q];
                pd += acc[q] * g1ad[h_ * 16 + o0 + q];
            }
            sp1s[((wv & 1) * 4 + h_) * 64 + lane] = ps;
            dp1s[((wv & 1) * 4 + h_) * 64 + lane] = pd;
        }
        __syncthreads();   // B3
        // ===== A1: attn1 single-pass + elu + fused inorm -> x2 =====
        {
            const int h_ = wv >> 1;
            const int o0 = (wv & 1) * 8;
            const float sv   = sp1s[h_ * 64 + lane] + sp1s[(4 + h_) * 64 + lane];
            const float dtot = dp1s[h_ * 64 + lane] + dp1s[(4 + h_) * 64 + lane];
            float sum = 0.0f;
            float acc[8];
            #pragma unroll
            for (int q = 0; q < 8; ++q) acc[q] = 0.0f;
            #pragma unroll
            for (int m4 = 0; m4 < 16; ++m4) {
                float e0 = __expf(leaky(sv + __shfl(dtot, m4 * 4 + 0)));
                float e1 = __expf(leaky(sv + __shfl(dtot, m4 * 4 + 1)));
                float e2 = __expf(leaky(sv + __shfl(dtot, m4 * 4 + 2)));
                float e3 = __expf(leaky(sv + __shfl(dtot, m4 * 4 + 3)));
                sum += e0 + e1 + e2 + e3;
                #pragma unroll
                for (int q = 0; q < 8; ++q) {
                    float4 hv = *reinterpret_cast<const float4*>(&hp1s[(h_ * 16 + o0 + q) * 64 + m4 * 4]);
                    acc[q] += e0 * hv.x + e1 * hv.y + e2 * hv.z + e3 * hv.w;
                }
            }
            float rs = 1.0f / sum;
            #pragma unroll
            for (int q = 0; q < 8; ++q) {
                float v = acc[q] * rs + g1b[o0 + q];
                v = (v > 0.0f) ? v : (__expf(v) - 1.0f);          // elu
                float sm = v, sq = v * v;                          // inorm over peds
                #pragma unroll
                for (int m = 1; m < 64; m <<= 1) { sm += __shfl_xor(sm, m); sq += __shfl_xor(sq, m); }
                float mean = sm * (1.0f / 64.0f);
                float var  = sq * (1.0f / 64.0f) - mean * mean;
                x2[(h_ * 16 + o0 + q) * 64 + lane] = (v - mean) * rsqrtf(var + 1e-5f);
            }
        }
        __syncthreads();   // B4
        // ===== G2: GAT2 projection + s2/d2 partials =====
        {
            float acc[4];
            #pragma unroll
            for (int q = 0; q < 4; ++q) acc[q] = 0.0f;
            for (int k8 = 0; k8 < 8; ++k8) {
                float xk[8];
                #pragma unroll
                for (int i = 0; i < 8; ++i) xk[i] = x2[(k8 * 8 + i) * 64 + lane];
                #pragma unroll
                for (int i = 0; i < 8; ++i)
                    #pragma unroll
                    for (int q = 0; q < 4; ++q)
                        acc[q] += g2w[(k8 * 8 + i) * 32 + wv * 4 + q] * xk[i];
            }
            float ps = 0.0f, pd = 0.0f;
            #pragma unroll
            for (int q = 0; q < 4; ++q) {
                hp2[(wv * 4 + q) * 64 + lane] = acc[q];
                ps += acc[q] * g2as[wv * 4 + q];
                pd += acc[q] * g2ad[wv * 4 + q];
            }
            sp2s[wv * 64 + lane] = ps;
            dp2s[wv * 64 + lane] = pd;
        }
        __syncthreads();   // B5 (hp2 overlays hp1s[0:2048]; hp1 dead after A1)
        // ===== A2: attn2 single-pass -> gin cols of AG (bf16 hi/lo) =====
        {
            float sv = 0.0f, dtot = 0.0f;
            #pragma unroll
            for (int w = 0; w < 8; ++w) { sv += sp2s[w * 64 + lane]; dtot += dp2s[w * 64 + lane]; }
            float sum = 0.0f;
            float acc[4];
            #pragma unroll
            for (int q = 0; q < 4; ++q) acc[q] = 0.0f;
            #pragma unroll
            for (int m4 = 0; m4 < 16; ++m4) {
                float e0 = __expf(leaky(sv + __shfl(dtot, m4 * 4 + 0)));
                float e1 = __expf(leaky(sv + __shfl(dtot, m4 * 4 + 1)));
                float e2 = __expf(leaky(sv + __shfl(dtot, m4 * 4 + 2)));
                float e3 = __expf(leaky(sv + __shfl(dtot, m4 * 4 + 3)));
                sum += e0 + e1 + e2 + e3;
                #pragma unroll
                for (int q = 0; q < 4; ++q) {
                    float4 hv = *reinterpret_cast<const float4*>(&hp2[(wv * 4 + q) * 64 + m4 * 4]);
                    acc[q] += e0 * hv.x + e1 * hv.y + e2 * hv.z + e3 * hv.w;
                }
            }
            float rs = 1.0f / sum;
            #pragma unroll
            for (int q = 0; q < 4; ++q) {
                float v = acc[q] * rs + g2b[wv * 4 + q];
                u16 h = bhi(v);
                AGh[lane * EAP + wv * 4 + q] = h;
                AGl[lane * EAP + wv * 4 + q] = bhi(v - bf2f(h));
            }
        }
        __syncthreads();   // B6: AG gin cols visible
        // ===== GR1: graph LSTM via MFMA =====
        float h2G[4];
        {
            f32x4 acc[4];
            #pragma unroll
            for (int mb = 0; mb < 4; ++mb) acc[mb] = (f32x4){0.f, 0.f, 0.f, 0.f};
            #pragma unroll
            for (int kb = 0; kb < 2; ++kb) {
                short8_t ah[4], al[4];
                #pragma unroll
                for (int mb = 0; mb < 4; ++mb) {
                    int off = (mb * 16 + pfrag) * EAP + kb * 32 + kg8;
                    ah[mb] = *(const short8_t*)&AGh[off];
                    al[mb] = *(const short8_t*)&AGl[off];
                }
                #pragma unroll
                for (int mb = 0; mb < 4; ++mb) {
                    acc[mb] = __builtin_amdgcn_mfma_f32_16x16x32_bf16(ah[mb], wfhG[kb], acc[mb], 0, 0, 0);
                    acc[mb] = __builtin_amdgcn_mfma_f32_16x16x32_bf16(ah[mb], wflG[kb], acc[mb], 0, 0, 0);
                    acc[mb] = __builtin_amdgcn_mfma_f32_16x16x32_bf16(al[mb], wfhG[kb], acc[mb], 0, 0, 0);
                }
            }
            const float bI = biasg[j2], bF = biasg[32 + j2], bG = biasg[64 + j2], bO = biasg[96 + j2];
            #pragma unroll
            for (int mb = 0; mb < 4; ++mb)
                xpose_update(acc[mb], lane, bI, bF, bG, bO, cG2[mb], h2G[mb]);
        }
        __syncthreads();   // B7: all MFMA reads of AG done
        // ===== GR2: write-back graph h2 =====
        #pragma unroll
        for (int mb = 0; mb < 4; ++mb) {
            int p = mb * 16 + lb2 * 4 + t_;
            u16 h = bhi(h2G[mb]);
            AGh[p * EAP + 32 + j2] = h;  AGl[p * EAP + 32 + j2] = bhi(h2G[mb] - bf2f(h));
        }
        if (t == OBS - 1) {
            #pragma unroll
            for (int mb = 0; mb < 4; ++mb) {
                int p = mb * 16 + lb2 * 4 + t_;
                wsG[j2 * NTOT + g * 64 + p] = h2G[mb];
            }
        }
        // no barrier: next reads of AG are behind B6 of t+1; AT reads behind B1 path
    } // t loop
}

// ============================ DECODER (round-5, unchanged) =================
__global__ __launch_bounds__(512, 1)
void stgat_dec(const float* __restrict__ obs,
               const float* __restrict__ zin,
               const float* __restrict__ w_ih_p,
               const float* __restrict__ w_hh_p,
               const float* __restrict__ b_ih_p,
               const float* __restrict__ b_hh_p,
               const float* __restrict__ w_out,
               const float* __restrict__ b_out,
               const float* __restrict__ wsT,    // traj_h^T [32][N]
               const float* __restrict__ wsG,    // graph_h^T [32][N]
               float* __restrict__ out)
{
    const int g    = blockIdx.x;
    const int lane = threadIdx.x & 63;
    const int wv   = __builtin_amdgcn_readfirstlane((int)(threadIdx.x >> 6));
    const int n    = g * NPED + lane;

    __shared__ __attribute__((aligned(16))) u16 Apack[4 * 64 * AP];
    __shared__ __attribute__((aligned(16))) short8_t WloS[18 * 3 * 64];
    u16* AhiA = Apack;
    u16* AloA = AhiA + 64 * AP;
    u16* AhiB = AloA + 64 * AP;
    u16* AloB = AhiB + 64 * AP;

    short8_t wfh[3][3];
    {
        const int col = lane & 15, lb = lane >> 4;
        #pragma unroll
        for (int s = 0; s < 3; ++s) {
            if (s < 2 || wv < 2) {
                int nb = wv + 8 * s;
                int gp = nb * 16 + col;
                int j = gp >> 2, ty = gp & 3;
                int orig = ty * HP_ + j;
                #pragma unroll
                for (int kb = 0; kb < 3; ++kb) {
                    short8_t fh, fl;
                    #pragma unroll
                    for (int jj = 0; jj < 8; ++jj) {
                        int k = kb * 32 + lb * 8 + jj;
                        float v;
                        if (k < 72)       v = w_hh_p[orig * HP_ + k];
                        else if (k == 72) v = w_ih_p[orig * 2 + 0];
                        else if (k == 73) v = w_ih_p[orig * 2 + 1];
                        else if (k == 74) v = b_ih_p[orig] + b_hh_p[orig];
                        else              v = 0.0f;
                        u16 hb = bhi(v);
                        fh[jj] = (short)hb;
                        fl[jj] = (short)bhi(v - bf2f(hb));
                    }
                    wfh[s][kb] = fh;
                    WloS[(nb * 3 + kb) * 64 + lane] = fl;
                }
            }
        }
    }

    {
        float px0 = obs[(7 * NTOT + n) * 3 + 0];
        float px1 = obs[(7 * NTOT + n) * 3 + 1];
        #pragma unroll
        for (int kk = 0; kk < 12; ++kk) {
            int k = wv + kk * 8;
            float va, vb;
            if (k < 32)       { va = wsT[k * NTOT + n];            vb = 0.0f; }
            else if (k < 64)  { va = vb = wsG[(k - 32) * NTOT + n]; }
            else if (k < 72)  { va = vb = zin[g * NZ_ + (k - 64)]; }
            else if (k == 72) { va = vb = px0; }
            else if (k == 73) { va = vb = px1; }
            else if (k == 74) { va = vb = 1.0f; }
            else              { va = vb = 0.0f; }
            u16 ha = bhi(va); u16 la = bhi(va - bf2f(ha));
            u16 hb = bhi(vb); u16 lb_ = bhi(vb - bf2f(hb));
            AhiA[lane * AP + k] = ha;  AloA[lane * AP + k] = la;
            AhiB[lane * AP + k] = hb;  AloB[lane * AP + k] = lb_;
        }
    }
    __syncthreads();

    float cstA[3][4], cstB[3][4];
    #pragma unroll
    for (int s = 0; s < 3; ++s)
        #pragma unroll
        for (int mb = 0; mb < 4; ++mb) { cstA[s][mb] = 0.0f; cstB[s][mb] = 0.0f; }

    const int lb2 = lane >> 4, u_ = (lane >> 2) & 3, t_ = lane & 3;
    const int pfrag = lane & 15, kgrp = (lane >> 4) * 8;

    for (int st = 0; st < FUT; ++st) {
        float h2A[3][4], h2B[3][4];
        {
            f32x4 acc[3][4];
            #pragma unroll
            for (int s = 0; s < 3; ++s)
                #pragma unroll
                for (int mb = 0; mb < 4; ++mb) acc[s][mb] = (f32x4){0.f, 0.f, 0.f, 0.f};
            #pragma unroll
            for (int kb = 0; kb < 3; ++kb) {
                short8_t ah[4], al[4];
                #pragma unroll
                for (int mb = 0; mb < 4; ++mb) {
                    int off = (mb * 16 + pfrag) * AP + kb * 32 + kgrp;
                    ah[mb] = *(const short8_t*)&AhiA[off];
                    al[mb] = *(const short8_t*)&AloA[off];
                }
                #pragma unroll
                for (int s = 0; s < 3; ++s) {
                    if (s < 2 || wv < 2) {
                        int nb = wv + 8 * s;
                        short8_t wl = WloS[(nb * 3 + kb) * 64 + lane];
                        #pragma unroll
                        for (int mb = 0; mb < 4; ++mb) {
                            acc[s][mb] = __builtin_amdgcn_mfma_f32_16x16x32_bf16(ah[mb], wfh[s][kb], acc[s][mb], 0, 0, 0);
                            acc[s][mb] = __builtin_amdgcn_mfma_f32_16x16x32_bf16(ah[mb], wl,         acc[s][mb], 0, 0, 0);
                            acc[s][mb] = __builtin_amdgcn_mfma_f32_16x16x32_bf16(al[mb], wfh[s][kb], acc[s][mb], 0, 0, 0);
                        }
                    }
                }
            }
            #pragma unroll
            for (int s = 0; s < 3; ++s)
                #pragma unroll
                for (int mb = 0; mb < 4; ++mb)
                    xpose_update(acc[s][mb], lane, 0.f, 0.f, 0.f, 0.f, cstA[s][mb], h2A[s][mb]);
        }
        {
            f32x4 acc[3][4];
            #pragma unroll
            for (int s = 0; s < 3; ++s)
                #pragma unroll
                for (int mb = 0; mb < 4; ++mb) acc[s][mb] = (f32x4){0.f, 0.f, 0.f, 0.f};
            #pragma unroll
            for (int kb = 0; kb < 3; ++kb) {
                short8_t bh[4], bl[4];
                #pragma unroll
                for (int mb = 0; mb < 4; ++mb) {
                    int off = (mb * 16 + pfrag) * AP + kb * 32 + kgrp;
                    bh[mb] = *(const short8_t*)&AhiB[off];
                    bl[mb] = *(const short8_t*)&AloB[off];
                }
                #pragma unroll
                for (int s = 0; s < 3; ++s) {
                    if (s < 2 || wv < 2) {
                        int nb = wv + 8 * s;
                        short8_t wl = WloS[(nb * 3 + kb) * 64 + lane];
                        #pragma unroll
                        for (int mb = 0; mb < 4; ++mb) {
                            acc[s][mb] = __builtin_amdgcn_mfma_f32_16x16x32_bf16(bh[mb], wfh[s][kb], acc[s][mb], 0, 0, 0);
                            acc[s][mb] = __builtin_amdgcn_mfma_f32_16x16x32_bf16(bh[mb], wl,         acc[s][mb], 0, 0, 0);
                            acc[s][mb] = __builtin_amdgcn_mfma_f32_16x16x32_bf16(bl[mb], wfh[s][kb], acc[s][mb], 0, 0, 0);
                        }
                    }
                }
            }
            #pragma unroll
            for (int s = 0; s < 3; ++s)
                #pragma unroll
                for (int mb = 0; mb < 4; ++mb)
                    xpose_update(acc[s][mb], lane, 0.f, 0.f, 0.f, 0.f, cstB[s][mb], h2B[s][mb]);
        }
        __syncthreads();   // B1
        #pragma unroll
        for (int s = 0; s < 3; ++s) {
            if (s < 2 || wv < 2) {
                int nb = wv + 8 * s;
                int j = nb * 4 + u_;
                #pragma unroll
                for (int mb = 0; mb < 4; ++mb) {
                    int p = mb * 16 + lb2 * 4 + t_;
                    float va = h2A[s][mb];
                    float vb = h2B[s][mb];
                    u16 ha = bhi(va);
                    AhiA[p * AP + j] = ha;  AloA[p * AP + j] = bhi(va - bf2f(ha));
                    u16 hb = bhi(vb);
                    AhiB[p * AP + j] = hb;  AloB[p * AP + j] = bhi(vb - bf2f(hb));
                }
            }
        }
        __syncthreads();   // B2
        if (wv == 0) {
            float s0 = 0.0f, s1_ = 0.0f;
            #pragma unroll
            for (int jb = 0; jb < 9; ++jb) {
                short8_t xha = *(const short8_t*)&AhiA[lane * AP + jb * 8];
                short8_t xla = *(const short8_t*)&AloA[lane * AP + jb * 8];
                short8_t xhb = *(const short8_t*)&AhiB[lane * AP + jb * 8];
                short8_t xlb = *(const short8_t*)&AloB[lane * AP + jb * 8];
                #pragma unroll
                for (int jj = 0; jj < 8; ++jj) {
                    int j = jb * 8 + jj;
                    float dh = (bf2f((u16)xha[jj]) + bf2f((u16)xla[jj]))
                             - (bf2f((u16)xhb[jj]) + bf2f((u16)xlb[jj]));
                    s0  += w_out[j] * dh;
                    s1_ += w_out[HP_ + j] * dh;
                }
            }
            float o0 = s0 + b_out[0], o1 = s1_ + b_out[1];
            *reinterpret_cast<float2*>(&out[(size_t)(st * NTOT + n) * 2]) = make_float2(o0, o1);
            u16 h0 = bhi(o0); u16 l0 = bhi(o0 - bf2f(h0));
            u16 h1 = bhi(o1); u16 l1 = bhi(o1 - bf2f(h1));
            AhiA[lane * AP + 72] = h0;  AloA[lane * AP + 72] = l0;
            AhiB[lane * AP + 72] = h0;  AloB[lane * AP + 72] = l0;
            AhiA[lane * AP + 73] = h1;  AloA[lane * AP + 73] = l1;
            AhiB[lane * AP + 73] = h1;  AloB[lane * AP + 73] = l1;
        }
        __syncthreads();   // B3
    }
}

extern "C" void kernel_launch(void* const* d_in, const int* in_sizes, int n_in,
                              void* d_out, int out_size, void* d_ws, size_t ws_size,
                              hipStream_t stream) {
    (void)in_sizes; (void)n_in; (void)out_size; (void)ws_size;
    float* wsT = (float*)d_ws;                 // [32][N]
    float* wsG = wsT + (size_t)HT_ * NTOT;     // [32][N]

    stgat_enc<<<dim3(NGR), dim3(512), 0, stream>>>(
        (const float*)d_in[0],
        (const float*)d_in[2],  (const float*)d_in[3],
        (const float*)d_in[4],  (const float*)d_in[5],
        (const float*)d_in[6],  (const float*)d_in[7],  (const float*)d_in[8],  (const float*)d_in[9],
        (const float*)d_in[10], (const float*)d_in[11], (const float*)d_in[12], (const float*)d_in[13],
        (const float*)d_in[14], (const float*)d_in[15], (const float*)d_in[16], (const float*)d_in[17],
        (const float*)d_in[18], (const float*)d_in[19], (const float*)d_in[20], (const float*)d_in[21],
        wsT, wsG);

    stgat_dec<<<dim3(NGR), dim3(512), 0, stream>>>(
        (const float*)d_in[0],
        (const float*)d_in[1],
        (const float*)d_in[22], (const float*)d_in[23],
        (const float*)d_in[24], (const float*)d_in[25],
        (const float*)d_in[26], (const float*)d_in[27],
        wsT, wsG,
        (float*)d_out);
}